// Round 7
// baseline (11130.730 us; speedup 1.0000x reference)
//
#include <hip/hip_runtime.h>
#include <hip/hip_bf16.h>

#define EPS 1e-5f
#define CSTR 292        // padded channel stride (8B-aligned bf16 rows, 16B f32)
#define PST 580         // partial row stride (floats): [blk][290 sum | 290 sumsq]
#define FPIX 15         // pixels per feat_k block-tile (15*17 = 255 threads)
#define RGRID 512       // persistent resid_k grid (2 blocks/CU -> safe co-residency)

typedef __hip_bfloat16 bf16;
typedef short s16x8 __attribute__((ext_vector_type(8)));
typedef float f32x4 __attribute__((ext_vector_type(4)));
typedef unsigned short u16x4 __attribute__((ext_vector_type(4)));
typedef unsigned short u16x8 __attribute__((ext_vector_type(8)));

__device__ inline float bf2f(unsigned short u) {
    union { unsigned int i; float f; } z; z.i = ((unsigned int)u) << 16; return z.f;
}
__device__ inline unsigned short f2bf(float f) {
    union { bf16 h; unsigned short u; } z; z.h = __float2bfloat16(f); return z.u;
}
__device__ inline unsigned short f2bf_trunc(float f) {
    union { float f; unsigned int u; } z; z.f = f; return (unsigned short)(z.u >> 16);
}

// ---- dense-kernel precompute into MFMA B-fragment order ---------------------
__device__ __forceinline__ void prep_frag(const float* w1, const float* w2,
                                          bf16* o, int kt, int nt, int l) {
#pragma unroll
    for (int e = 0; e < 8; ++e) {
        int k = kt * 32 + ((l >> 4) << 3) + e;
        int n = nt * 16 + (l & 15);
        float v = 0.f;
        if (k < 289 && n < 289)
            v = w1[(n / 17) * 17 + (k / 17)] * w2[(k % 17) * 17 + (n % 17)];
        o[e] = __float2bfloat16(v);
    }
}

__global__ void prep11_all_k(const float* __restrict__ W1all, const float* __restrict__ W2all,
                             bf16* __restrict__ Bsw) {
    int bi = blockIdx.x;                // 27*190
    int cv = bi / 190, r = bi - cv * 190;
    int kt = r / 19, nt = r - kt * 19;
    prep_frag(W1all + (size_t)cv * 289, W2all + (size_t)cv * 289,
              Bsw + (size_t)bi * 512 + threadIdx.x * 8, kt, nt, threadIdx.x);
}

__global__ void prep33_k(const float* __restrict__ W1, const float* __restrict__ W2,
                         bf16* __restrict__ Bsw) {
    int bi = blockIdx.x;                // 9*190
    int tap = bi / 190; int r = bi - tap * 190;
    int kt = r / 19, nt = r - kt * 19;
    prep_frag(W1 + (size_t)tap * 289, W2 + (size_t)tap * 289,
              Bsw + (size_t)bi * 512 + threadIdx.x * 8, kt, nt, threadIdx.x);
}

// all 3x3 fragment sets for residual blocks 1..8, one launch (into dead-A region)
__global__ void prep33all_k(const float* __restrict__ W1, const float* __restrict__ W2,
                            bf16* __restrict__ Bsw) {
    int fi = blockIdx.x * 4 + (threadIdx.x >> 6);   // 3420 blocks x 4 frags
    int l = threadIdx.x & 63;
    int kb = fi / 1710, r = fi - kb * 1710;         // kb: 0..7 -> block k=kb+1
    int tap = r / 190; int rr = r - tap * 190;
    int kt = rr / 19, nt = rr - kt * 19;
    const float* w1 = W1 + (long)(kb + 1) * 9 * 289 + (long)tap * 289;
    const float* w2 = W2 + (long)(kb + 1) * 9 * 289 + (long)tap * 289;
    prep_frag(w1, w2, Bsw + (size_t)fi * 512 + l * 8, kt, nt, l);
}

// ---- features: 3x3 s2 tensor conv, LDS-tiled stores + fused BN stats --------
__global__ __launch_bounds__(256) void feat_k(
    const float* __restrict__ x, bf16* __restrict__ out,
    const float* __restrict__ W1, const float* __restrict__ W2,
    float* __restrict__ partial) {
    __shared__ float W1s[459], W2s[153];
    __shared__ float S[289], SS[289];
    __shared__ bf16 T[FPIX][292];
    int tid = threadIdx.x;
    for (int i = tid; i < 459; i += 256) W1s[i] = W1[i];
    for (int i = tid; i < 153; i += 256) W2s[i] = W2[i];
    for (int i = tid; i < 289; i += 256) { S[i] = 0.f; SS[i] = 0.f; }
    if (tid < FPIX * 3) T[tid / 3][289 + tid % 3] = __float2bfloat16(0.f);
    int lp = tid / 17, p = tid - lp * 17;
    bool act = tid < 255;
    float sacc[17], qacc[17];
#pragma unroll
    for (int q = 0; q < 17; ++q) { sacc[q] = 0.f; qacc[q] = 0.f; }
    const int NT = (204800 + FPIX - 1) / FPIX;      // 13654
    __syncthreads();
    for (int t = blockIdx.x; t < NT; t += gridDim.x) {
        int pix0 = t * FPIX;
        int pix = pix0 + lp;
        if (act && pix < 204800) {
            int b = pix / 6400; int rr = pix - b * 6400;
            int oh = rr / 80, ow = rr - oh * 80;
            float y[17];
#pragma unroll
            for (int q = 0; q < 17; ++q) y[q] = 0.f;
            for (int di = 0; di < 3; ++di) {
                int ih = oh * 2 + di - 1;
                if (ih < 0 || ih >= 160) continue;
                for (int dj = 0; dj < 3; ++dj) {
                    int iw = ow * 2 + dj - 1;
                    if (iw < 0 || iw >= 160) continue;
                    int k = di * 3 + dj;
                    long xb = (long)b * 76800 + ih * 160 + iw;
                    float dot = W1s[(k * 17 + p) * 3 + 0] * x[xb]
                              + W1s[(k * 17 + p) * 3 + 1] * x[xb + 25600]
                              + W1s[(k * 17 + p) * 3 + 2] * x[xb + 51200];
#pragma unroll
                    for (int q = 0; q < 17; ++q) y[q] += dot * W2s[k * 17 + q];
                }
            }
#pragma unroll
            for (int q = 0; q < 17; ++q) {
                bf16 h = __float2bfloat16(y[q]);
                T[lp][p * 17 + q] = h;
                float vv = __bfloat162float(h);     // stats on rounded value
                sacc[q] += vv; qacc[q] += vv * vv;
            }
        }
        __syncthreads();
        int nv = 204800 - pix0; if (nv > FPIX) nv = FPIX;
        for (int idx = tid; idx < nv * 73; idx += 256) {
            int row = idx / 73, j = idx - row * 73;
            *(u16x4*)(out + (long)(pix0 + row) * CSTR + j * 4) =
                *(const u16x4*)(&T[row][j * 4]);
        }
        __syncthreads();
    }
    if (act) {
#pragma unroll
        for (int q = 0; q < 17; ++q) {
            atomicAdd(&S[p * 17 + q], sacc[q]);
            atomicAdd(&SS[p * 17 + q], qacc[q]);
        }
    }
    __syncthreads();
    for (int i = tid; i < 289; i += 256) {
        partial[(long)blockIdx.x * PST + i] = S[i];
        partial[(long)blockIdx.x * PST + 290 + i] = SS[i];
    }
}

// ---- MFMA GEMM conv, MROWS=16*MT, async-stage pipeline (T14) ----------------
template <typename TI, typename TO, int TAPS, bool DUAL, int MT>
__global__ __launch_bounds__(256, MT == 2 ? 3 : 5) void gemm_k(
    const TI* __restrict__ in1, const TI* __restrict__ in2, TO* __restrict__ out,
    const bf16* __restrict__ Bs, const float* __restrict__ scshAll, int bn1, int bn2,
    const float* __restrict__ alphaPtr, float* __restrict__ partial,
    int Hin, int Win, int Hout, int Wout, int stride) {
    constexpr int MROWS = 16 * MT;
    constexpr int SITS = (37 * MROWS + 255) / 256;     // 3 (MT1) or 5 (MT2)
    static_assert(MROWS * 304 * sizeof(TO) <= 2 * MROWS * 640, "epilogue must fit As");
    __shared__ char As[2 * MROWS * 640];        // hi buffer | lo buffer
    __shared__ float sc1[296], sh1[296];
    __shared__ float sc2[DUAL ? 296 : 1], sh2[DUAL ? 296 : 1];
    __shared__ long gb00[MROWS];
    __shared__ int ihw0[MROWS];                 // (ih0+1)<<16 | (iw0+1)
    int tid = threadIdx.x;
    int HWin = Hin * Win, HWout = Hout * Wout;
    int pix0 = blockIdx.x * MROWS;
    for (int i = tid; i < 296; i += 256) {
        int cc = i < 289 ? i : 0;
        sc1[i] = scshAll[bn1 * 578 + cc]; sh1[i] = scshAll[bn1 * 578 + 289 + cc];
        if constexpr (DUAL) {
            sc2[i] = scshAll[bn2 * 578 + cc]; sh2[i] = scshAll[bn2 * 578 + 289 + cc];
        }
    }
    if (tid < MROWS) {
        int op = pix0 + tid;
        int b = op / HWout; int rr = op - b * HWout;
        int oh = rr / Wout, ow = rr - oh * Wout;
        int ih0 = oh * stride + (TAPS == 9 ? -1 : 0);
        int iw0 = ow * stride + (TAPS == 9 ? -1 : 0);
        gb00[tid] = ((long)b * HWin + (long)ih0 * Win + iw0) * CSTR;
        ihw0[tid] = ((ih0 + 1) << 16) | (iw0 + 1);
    }
    if (tid < 8 * MROWS) {
        int half = tid / (4 * MROWS), r = (tid >> 2) & (MROWS - 1), c = tid & 3;
        int byte = (r * 640 + 576 + c * 16) ^ ((r & 7) << 4);
        *(u16x8*)(As + half * (MROWS * 640) + byte) = (u16x8){0, 0, 0, 0, 0, 0, 0, 0};
    }
    float alpha = DUAL ? 0.f : *alphaPtr;
    int w = tid >> 6, l = tid & 63;
    int nt0 = w * 5;
    int lane_n = l & 15;
    int kbyte = (l >> 4) << 4;
    f32x4 acc[MT][5];
#pragma unroll
    for (int m = 0; m < MT; ++m)
#pragma unroll
        for (int j = 0; j < 5; ++j) acc[m][j] = (f32x4){0.f, 0.f, 0.f, 0.f};
    __syncthreads();

    bool cact[SITS]; int cih[SITS], ciw[SITS], cwb[SITS], ck0[SITS]; long cgb[SITS];
#pragma unroll
    for (int it = 0; it < SITS; ++it) {
        int cid = it * 256 + tid;
        cact[it] = cid < 37 * MROWS;
        int row = cact[it] ? cid / 37 : 0;
        int j = cid - row * 37;
        ck0[it] = j * 8;
        cgb[it] = gb00[row] + j * 8;
        int pk = ihw0[row];
        cih[it] = (pk >> 16) - 1; ciw[it] = (pk & 0xffff) - 1;
        cwb[it] = (row * 640 + j * 16) ^ ((row & 7) << 4);
    }
    bool vld[SITS];
    u16x4 rh1[SITS][2]; f32x4 rf1[SITS][2];             // in1 raw (one used per TI)
    u16x4 rh2[DUAL ? SITS : 1][2]; f32x4 rf2[DUAL ? SITS : 1][2];

    auto LOAD = [&](int tap) {
        int di = (TAPS == 9) ? tap / 3 : 0;
        int dj = (TAPS == 9) ? tap - di * 3 : 0;
        long toff = (long)(di * Win + dj) * CSTR;
#pragma unroll
        for (int it = 0; it < SITS; ++it) {
            vld[it] = false;
            if (cact[it]) {
                int ih = cih[it] + di, iw = ciw[it] + dj;
                if (ih >= 0 && ih < Hin && iw >= 0 && iw < Win) {
                    vld[it] = true;
                    long gb = cgb[it] + toff;
                    if constexpr (sizeof(TI) == 2) {
                        rh1[it][0] = *(const u16x4*)((const bf16*)in1 + gb);
                        rh1[it][1] = *(const u16x4*)((const bf16*)in1 + gb + 4);
                        if constexpr (DUAL) {
                            rh2[it][0] = *(const u16x4*)((const bf16*)in2 + gb);
                            rh2[it][1] = *(const u16x4*)((const bf16*)in2 + gb + 4);
                        }
                    } else {
                        rf1[it][0] = *(const f32x4*)((const float*)in1 + gb);
                        rf1[it][1] = *(const f32x4*)((const float*)in1 + gb + 4);
                        if constexpr (DUAL) {
                            rf2[it][0] = *(const f32x4*)((const float*)in2 + gb);
                            rf2[it][1] = *(const f32x4*)((const float*)in2 + gb + 4);
                        }
                    }
                }
            }
        }
    };

    auto WRITE = [&]() {
#pragma unroll
        for (int it = 0; it < SITS; ++it) {
            if (!cact[it]) continue;
            float v[8];
            if (vld[it]) {
                int k0 = ck0[it];
                float r[8];
                if constexpr (sizeof(TI) == 2) {
#pragma unroll
                    for (int e = 0; e < 4; ++e) {
                        r[e] = bf2f(rh1[it][0][e]); r[4 + e] = bf2f(rh1[it][1][e]);
                    }
                } else {
#pragma unroll
                    for (int e = 0; e < 4; ++e) {
                        r[e] = rf1[it][0][e]; r[4 + e] = rf1[it][1][e];
                    }
                }
#pragma unroll
                for (int e = 0; e < 8; ++e) v[e] = sc1[k0 + e] * r[e] + sh1[k0 + e];
                if constexpr (DUAL) {
                    float q[8];
                    if constexpr (sizeof(TI) == 2) {
#pragma unroll
                        for (int e = 0; e < 4; ++e) {
                            q[e] = bf2f(rh2[it][0][e]); q[4 + e] = bf2f(rh2[it][1][e]);
                        }
                    } else {
#pragma unroll
                        for (int e = 0; e < 4; ++e) {
                            q[e] = rf2[it][0][e]; q[4 + e] = rf2[it][1][e];
                        }
                    }
#pragma unroll
                    for (int e = 0; e < 8; ++e) v[e] += sc2[k0 + e] * q[e] + sh2[k0 + e];
                } else {
#pragma unroll
                    for (int e = 0; e < 8; ++e) v[e] = v[e] >= 0.f ? v[e] : alpha * v[e];
                }
#pragma unroll
                for (int e = 0; e < 8; ++e) if (ck0[it] + e > 288) v[e] = 0.f;
            } else {
#pragma unroll
                for (int e = 0; e < 8; ++e) v[e] = 0.f;
            }
            u16x4 hi0, hi1, lo0, lo1;
#pragma unroll
            for (int e = 0; e < 4; ++e) {
                unsigned short h = f2bf(v[e]);
                hi0[e] = h; lo0[e] = f2bf_trunc(v[e] - bf2f(h));
                unsigned short h2 = f2bf(v[4 + e]);
                hi1[e] = h2; lo1[e] = f2bf_trunc(v[4 + e] - bf2f(h2));
            }
            int byte = cwb[it];
            *(u16x4*)(As + byte) = hi0;
            *(u16x4*)(As + byte + 8) = hi1;
            *(u16x4*)(As + MROWS * 640 + byte) = lo0;
            *(u16x4*)(As + MROWS * 640 + byte + 8) = lo1;
        }
    };

    LOAD(0);
#pragma unroll 1
    for (int tap = 0; tap < TAPS; ++tap) {
        WRITE();
        if (tap + 1 < TAPS) LOAD(tap + 1);      // in flight across the K-loop
        __syncthreads();
        const bf16* bp = Bs + (size_t)tap * 97280 + (size_t)l * 8;
        int swz = (lane_n & 7) << 4;
        __builtin_amdgcn_s_setprio(1);
#pragma unroll 2
        for (int kt = 0; kt < 10; ++kt) {
            s16x8 ah[MT], al[MT];
#pragma unroll
            for (int m = 0; m < MT; ++m) {
                int ro = ((m * 16 + lane_n) * 640 + kbyte + kt * 64) ^ swz;
                ah[m] = *(const s16x8*)(As + ro);
                al[m] = *(const s16x8*)(As + MROWS * 640 + ro);
            }
#pragma unroll
            for (int j = 0; j < 5; ++j) {
                if (j < 4 || w < 3) {
                    s16x8 bfr = *(const s16x8*)(bp + (size_t)(kt * 19 + nt0 + j) * 512);
#pragma unroll
                    for (int m = 0; m < MT; ++m) {
                        acc[m][j] = __builtin_amdgcn_mfma_f32_16x16x32_bf16(
                            ah[m], bfr, acc[m][j], 0, 0, 0);
                        acc[m][j] = __builtin_amdgcn_mfma_f32_16x16x32_bf16(
                            al[m], bfr, acc[m][j], 0, 0, 0);
                    }
                }
            }
        }
        __builtin_amdgcn_s_setprio(0);
        __syncthreads();
    }
    {
#pragma unroll
        for (int j = 0; j < 5; ++j) {
            float s = 0.f, ss = 0.f;
            if (j < 4 || w < 3) {
#pragma unroll
                for (int m = 0; m < MT; ++m)
#pragma unroll
                    for (int e = 0; e < 4; ++e) {
                        float v = acc[m][j][e];
                        s += v; ss += v * v;
                    }
            }
            s += __shfl_xor(s, 16); ss += __shfl_xor(ss, 16);
            s += __shfl_xor(s, 32); ss += __shfl_xor(ss, 32);
            int n = (nt0 + j) * 16 + lane_n;
            if (l < 16 && n < 289 && (j < 4 || w < 3)) {
                partial[(long)blockIdx.x * PST + n] = s;
                partial[(long)blockIdx.x * PST + 290 + n] = ss;
            }
        }
    }
    {
        TO* ep = (TO*)As;
        int re = (l >> 4) << 2;
#pragma unroll
        for (int m = 0; m < MT; ++m) {
#pragma unroll
            for (int j = 0; j < 5; ++j) {
                if (j < 4 || w < 3) {
                    int n = (nt0 + j) * 16 + lane_n;
#pragma unroll
                    for (int e = 0; e < 4; ++e) {
                        if constexpr (sizeof(TO) == 2)
                            ep[(m * 16 + re + e) * 304 + n] = __float2bfloat16(acc[m][j][e]);
                        else
                            ((float*)ep)[(m * 16 + re + e) * 304 + n] = acc[m][j][e];
                    }
                }
            }
        }
        __syncthreads();
        for (int cid = tid; cid < MROWS * 73; cid += 256) {
            int row = cid / 73, j = cid - row * 73;
            long g = (long)(pix0 + row) * CSTR + j * 4;
            if constexpr (sizeof(TO) == 2) {
                u16x4 v = *(const u16x4*)((const bf16*)ep + row * 304 + j * 4);
                *(u16x4*)((bf16*)out + g) = v;
            } else {
                f32x4 v = *(const f32x4*)((const float*)ep + row * 304 + j * 4);
                *(f32x4*)((float*)out + g) = v;
            }
        }
    }
}

__device__ __forceinline__ void fin_one(const float* partial, const float* g,
                                        const float* bt, float* scshAll,
                                        int bnid, float invN, int GN, int c) {
    float s = 0.f, ss = 0.f;
    for (int k = threadIdx.x; k < GN; k += 256) {
        s += partial[(long)k * PST + c];
        ss += partial[(long)k * PST + 290 + c];
    }
    for (int o = 32; o; o >>= 1) { s += __shfl_down(s, o); ss += __shfl_down(ss, o); }
    __shared__ float ls[4], lss[4];
    int w = threadIdx.x >> 6;
    if ((threadIdx.x & 63) == 0) { ls[w] = s; lss[w] = ss; }
    __syncthreads();
    if (threadIdx.x == 0) {
        s = ls[0] + ls[1] + ls[2] + ls[3];
        ss = lss[0] + lss[1] + lss[2] + lss[3];
        float m = s * invN;
        float v = ss * invN - m * m;
        float sc = g[c] * rsqrtf(v + EPS);
        scshAll[bnid * 578 + c] = sc;
        scshAll[bnid * 578 + 289 + c] = bt[c] - m * sc;
    }
    __syncthreads();
}

__global__ void finalize_k(const float* __restrict__ partial, const float* __restrict__ g,
                           const float* __restrict__ bt, float* __restrict__ scshAll,
                           int bnid, float invN, int GN) {
    fin_one(partial, g, bt, scshAll, bnid, invN, GN, blockIdx.x);
}

// two independent stats sets (possibly different partials / GN / invN)
__global__ void finalize2v_k(const float* __restrict__ pA, const float* __restrict__ pB,
                             const float* __restrict__ gAll, const float* __restrict__ btAll,
                             float* __restrict__ scshAll, int bnA, int bnB,
                             float invA, int GNa, float invB, int GNb) {
    int q = blockIdx.x / 289, c = blockIdx.x - q * 289;
    const float* p = q ? pB : pA;
    int bnid = q ? bnB : bnA;
    fin_one(p, gAll + bnid * 289, btAll + bnid * 289, scshAll, bnid,
            q ? invB : invA, q ? GNb : GNa, c);
}

// ---- persistent residual-tail kernel: blocks 2..8 in ONE launch -------------
// 512 blocks (2/CU guaranteed co-resident: 25.5KB LDS, launch_bounds(256,2)).
// Grid barrier: monotonic device-scope counter + threadfence release/acquire.
// Per k: gemm2(800 jobs) | bar | fin2(578) | bar | y2 TAPS9 (800, MROWS16) |
// bar | fin(289) | bar | y3 (800) | bar | fin(289) | bar. Pointers rotate.
__global__ __launch_bounds__(256, 2) void resid_k(
    float* E, float* D, float* F,
    const bf16* __restrict__ B11all, const bf16* __restrict__ B33all,
    float* __restrict__ scsh, const float* __restrict__ bng,
    const float* __restrict__ bnbt, const float* __restrict__ pa,
    float* __restrict__ partial, float* __restrict__ partial2,
    unsigned* __restrict__ bar) {
    __shared__ char As[2 * 16 * 640];           // 20 KiB
    __shared__ float sc1[296], sh1[296], sc2[296], sh2[296];
    __shared__ long gb00[16];
    __shared__ int ihw0[16];
    int tid = threadIdx.x, bi = blockIdx.x;
    int w = tid >> 6, l = tid & 63;
    int nt0 = w * 5, lane_n = l & 15, kbyte = (l >> 4) << 4;
    int swz = (lane_n & 7) << 4;
    unsigned barn = 0;
    const float inv20 = 1.f / 12800.f;

    auto GBAR = [&]() {
        __syncthreads();
        if (tid == 0) {
            __threadfence();                    // release prior writes
            atomicAdd(bar, 1u);
            barn += (unsigned)RGRID;
            while (__hip_atomic_load(bar, __ATOMIC_ACQUIRE,
                                     __HIP_MEMORY_SCOPE_AGENT) < barn)
                __builtin_amdgcn_s_sleep(2);
            __threadfence();                    // acquire others' writes
        }
        __syncthreads();
    };

    auto LOADSC = [&](int bn1, int bn2, bool dual) {
        for (int i = tid; i < 296; i += 256) {
            int cc = i < 289 ? i : 0;
            sc1[i] = scsh[bn1 * 578 + cc]; sh1[i] = scsh[bn1 * 578 + 289 + cc];
            if (dual) { sc2[i] = scsh[bn2 * 578 + cc]; sh2[i] = scsh[bn2 * 578 + 289 + cc]; }
        }
        __syncthreads();
    };

    // single-input staged gemm, float in/out, MROWS=16, runtime TAPS (20x20 s1)
    auto RUN1 = [&](int job, int TAPS, const float* in, float* out,
                    const bf16* Bs, float alpha, float* part) {
        int pix0 = job * 16;
        if (tid < 16) {
            int op = pix0 + tid;
            int b = op / 400; int rr = op - b * 400;
            int oh = rr / 20, ow = rr - oh * 20;
            int off = (TAPS == 9) ? -1 : 0;
            int ih0 = oh + off, iw0 = ow + off;
            gb00[tid] = ((long)b * 400 + (long)ih0 * 20 + iw0) * CSTR;
            ihw0[tid] = ((ih0 + 1) << 16) | (iw0 + 1);
        }
        if (tid < 128) {    // re-zero LDS tails (epilogue corrupts them)
            int half = tid >> 6, r = (tid >> 2) & 15, c = tid & 3;
            int byte = (r * 640 + 576 + c * 16) ^ ((r & 7) << 4);
            *(u16x8*)(As + half * 10240 + byte) = (u16x8){0, 0, 0, 0, 0, 0, 0, 0};
        }
        f32x4 acc[5];
#pragma unroll
        for (int j = 0; j < 5; ++j) acc[j] = (f32x4){0.f, 0.f, 0.f, 0.f};
        __syncthreads();
        bool cact[3]; int cih[3], ciw[3], cwb[3], ck0[3]; long cgb[3];
#pragma unroll
        for (int it = 0; it < 3; ++it) {
            int cid = it * 256 + tid;
            cact[it] = cid < 592;
            int row = cact[it] ? cid / 37 : 0;
            int j = cid - row * 37;
            ck0[it] = j * 8;
            cgb[it] = gb00[row] + j * 8;
            int pk = ihw0[row];
            cih[it] = (pk >> 16) - 1; ciw[it] = (pk & 0xffff) - 1;
            cwb[it] = (row * 640 + j * 16) ^ ((row & 7) << 4);
        }
        for (int tap = 0; tap < TAPS; ++tap) {
            int di = (TAPS == 9) ? tap / 3 : 0;
            int dj = (TAPS == 9) ? tap - di * 3 : 0;
            long toff = (long)(di * 20 + dj) * CSTR;
#pragma unroll
            for (int it = 0; it < 3; ++it) {
                if (!cact[it]) continue;
                float v[8];
                int ih = cih[it] + di, iw = ciw[it] + dj;
                if (ih >= 0 && ih < 20 && iw >= 0 && iw < 20) {
                    long gb = cgb[it] + toff;
                    f32x4 a = *(const f32x4*)(in + gb);
                    f32x4 b2 = *(const f32x4*)(in + gb + 4);
                    int k0 = ck0[it];
#pragma unroll
                    for (int e = 0; e < 4; ++e) {
                        v[e] = sc1[k0 + e] * a[e] + sh1[k0 + e];
                        v[4 + e] = sc1[k0 + 4 + e] * b2[e] + sh1[k0 + 4 + e];
                    }
#pragma unroll
                    for (int e = 0; e < 8; ++e) {
                        v[e] = v[e] >= 0.f ? v[e] : alpha * v[e];
                        if (k0 + e > 288) v[e] = 0.f;
                    }
                } else {
#pragma unroll
                    for (int e = 0; e < 8; ++e) v[e] = 0.f;
                }
                u16x4 hi0, hi1, lo0, lo1;
#pragma unroll
                for (int e = 0; e < 4; ++e) {
                    unsigned short h = f2bf(v[e]);
                    hi0[e] = h; lo0[e] = f2bf_trunc(v[e] - bf2f(h));
                    unsigned short h2 = f2bf(v[4 + e]);
                    hi1[e] = h2; lo1[e] = f2bf_trunc(v[4 + e] - bf2f(h2));
                }
                int byte = cwb[it];
                *(u16x4*)(As + byte) = hi0;
                *(u16x4*)(As + byte + 8) = hi1;
                *(u16x4*)(As + 10240 + byte) = lo0;
                *(u16x4*)(As + 10240 + byte + 8) = lo1;
            }
            __syncthreads();
            const bf16* bp = Bs + (size_t)tap * 97280 + (size_t)l * 8;
            __builtin_amdgcn_s_setprio(1);
#pragma unroll 2
            for (int kt = 0; kt < 10; ++kt) {
                int ro = (lane_n * 640 + kbyte + kt * 64) ^ swz;
                s16x8 ah = *(const s16x8*)(As + ro);
                s16x8 al = *(const s16x8*)(As + 10240 + ro);
#pragma unroll
                for (int j = 0; j < 5; ++j) {
                    if (j < 4 || w < 3) {
                        s16x8 bfr = *(const s16x8*)(bp + (size_t)(kt * 19 + nt0 + j) * 512);
                        acc[j] = __builtin_amdgcn_mfma_f32_16x16x32_bf16(ah, bfr, acc[j], 0, 0, 0);
                        acc[j] = __builtin_amdgcn_mfma_f32_16x16x32_bf16(al, bfr, acc[j], 0, 0, 0);
                    }
                }
            }
            __builtin_amdgcn_s_setprio(0);
            __syncthreads();
        }
#pragma unroll
        for (int j = 0; j < 5; ++j) {
            float s = 0.f, ss = 0.f;
            if (j < 4 || w < 3) {
#pragma unroll
                for (int e = 0; e < 4; ++e) { float v = acc[j][e]; s += v; ss += v * v; }
            }
            s += __shfl_xor(s, 16); ss += __shfl_xor(ss, 16);
            s += __shfl_xor(s, 32); ss += __shfl_xor(ss, 32);
            int n = (nt0 + j) * 16 + lane_n;
            if (l < 16 && n < 289 && (j < 4 || w < 3)) {
                part[(long)job * PST + n] = s;
                part[(long)job * PST + 290 + n] = ss;
            }
        }
        float* ep = (float*)As;
        int re = (l >> 4) << 2;
#pragma unroll
        for (int j = 0; j < 5; ++j) {
            if (j < 4 || w < 3) {
                int n = (nt0 + j) * 16 + lane_n;
#pragma unroll
                for (int e = 0; e < 4; ++e) ep[(re + e) * 304 + n] = acc[j][e];
            }
        }
        __syncthreads();
        for (int cid = tid; cid < 16 * 73; cid += 256) {
            int row = cid / 73, j = cid - row * 73;
            long g = (long)(pix0 + row) * CSTR + j * 4;
            f32x4 v = *(const f32x4*)(ep + row * 304 + j * 4);
            *(f32x4*)(out + g) = v;
        }
        __syncthreads();
    };

    // dual-input dual-B gemm (idn+y1 merged), float, MROWS=16, 1x1 stride-1
    auto RUN2 = [&](int job, const float* in1, const float* in2,
                    float* out1, float* out2,
                    const bf16* Bs1, const bf16* Bs2,
                    float* part1, float* part2) {
        int pix0 = job * 16;
        if (tid < 128) {
            int half = tid >> 6, r = (tid >> 2) & 15, c = tid & 3;
            int byte = (r * 640 + 576 + c * 16) ^ ((r & 7) << 4);
            *(u16x8*)(As + half * 10240 + byte) = (u16x8){0, 0, 0, 0, 0, 0, 0, 0};
        }
        f32x4 acc1[5], acc2[5];
#pragma unroll
        for (int j = 0; j < 5; ++j) {
            acc1[j] = (f32x4){0.f, 0.f, 0.f, 0.f};
            acc2[j] = (f32x4){0.f, 0.f, 0.f, 0.f};
        }
        __syncthreads();
#pragma unroll
        for (int it = 0; it < 3; ++it) {
            int cid = it * 256 + tid;
            if (cid < 592) {
                int row = cid / 37, j = cid - row * 37, k0 = j * 8;
                long gb = (long)(pix0 + row) * CSTR + k0;
                f32x4 a = *(const f32x4*)(in1 + gb), b = *(const f32x4*)(in1 + gb + 4);
                f32x4 c = *(const f32x4*)(in2 + gb), d = *(const f32x4*)(in2 + gb + 4);
                float v[8];
#pragma unroll
                for (int e = 0; e < 4; ++e) {
                    v[e] = sc1[k0 + e] * a[e] + sh1[k0 + e] + sc2[k0 + e] * c[e] + sh2[k0 + e];
                    v[4 + e] = sc1[k0 + 4 + e] * b[e] + sh1[k0 + 4 + e]
                             + sc2[k0 + 4 + e] * d[e] + sh2[k0 + 4 + e];
                }
#pragma unroll
                for (int e = 0; e < 8; ++e) if (k0 + e > 288) v[e] = 0.f;
                u16x4 hi0, hi1, lo0, lo1;
#pragma unroll
                for (int e = 0; e < 4; ++e) {
                    unsigned short h = f2bf(v[e]);
                    hi0[e] = h; lo0[e] = f2bf_trunc(v[e] - bf2f(h));
                    unsigned short h2 = f2bf(v[4 + e]);
                    hi1[e] = h2; lo1[e] = f2bf_trunc(v[4 + e] - bf2f(h2));
                }
                int byte = (row * 640 + j * 16) ^ ((row & 7) << 4);
                *(u16x4*)(As + byte) = hi0;
                *(u16x4*)(As + byte + 8) = hi1;
                *(u16x4*)(As + 10240 + byte) = lo0;
                *(u16x4*)(As + 10240 + byte + 8) = lo1;
            }
        }
        __syncthreads();
        const bf16* bp1 = Bs1 + (size_t)l * 8;
        const bf16* bp2 = Bs2 + (size_t)l * 8;
        __builtin_amdgcn_s_setprio(1);
#pragma unroll 2
        for (int kt = 0; kt < 10; ++kt) {
            int ro = (lane_n * 640 + kbyte + kt * 64) ^ swz;
            s16x8 ah = *(const s16x8*)(As + ro);
            s16x8 al = *(const s16x8*)(As + 10240 + ro);
#pragma unroll
            for (int j = 0; j < 5; ++j) {
                if (j < 4 || w < 3) {
                    size_t fo = (size_t)(kt * 19 + nt0 + j) * 512;
                    s16x8 b1 = *(const s16x8*)(bp1 + fo);
                    acc1[j] = __builtin_amdgcn_mfma_f32_16x16x32_bf16(ah, b1, acc1[j], 0, 0, 0);
                    acc1[j] = __builtin_amdgcn_mfma_f32_16x16x32_bf16(al, b1, acc1[j], 0, 0, 0);
                    s16x8 b2 = *(const s16x8*)(bp2 + fo);
                    acc2[j] = __builtin_amdgcn_mfma_f32_16x16x32_bf16(ah, b2, acc2[j], 0, 0, 0);
                    acc2[j] = __builtin_amdgcn_mfma_f32_16x16x32_bf16(al, b2, acc2[j], 0, 0, 0);
                }
            }
        }
        __builtin_amdgcn_s_setprio(0);
        __syncthreads();
#pragma unroll
        for (int j = 0; j < 5; ++j) {
            float s1 = 0.f, q1 = 0.f, s2 = 0.f, q2 = 0.f;
            if (j < 4 || w < 3) {
#pragma unroll
                for (int e = 0; e < 4; ++e) {
                    float v1 = acc1[j][e]; s1 += v1; q1 += v1 * v1;
                    float v2 = acc2[j][e]; s2 += v2; q2 += v2 * v2;
                }
            }
            s1 += __shfl_xor(s1, 16); q1 += __shfl_xor(q1, 16);
            s1 += __shfl_xor(s1, 32); q1 += __shfl_xor(q1, 32);
            s2 += __shfl_xor(s2, 16); q2 += __shfl_xor(q2, 16);
            s2 += __shfl_xor(s2, 32); q2 += __shfl_xor(q2, 32);
            int n = (nt0 + j) * 16 + lane_n;
            if (l < 16 && n < 289 && (j < 4 || w < 3)) {
                part1[(long)job * PST + n] = s1;
                part1[(long)job * PST + 290 + n] = q1;
                part2[(long)job * PST + n] = s2;
                part2[(long)job * PST + 290 + n] = q2;
            }
        }
        float* ep = (float*)As;
        int re = (l >> 4) << 2;
#pragma unroll
        for (int pass = 0; pass < 2; ++pass) {
            const f32x4* ac = pass ? acc2 : acc1;
            float* op = pass ? out2 : out1;
#pragma unroll
            for (int j = 0; j < 5; ++j) {
                if (j < 4 || w < 3) {
                    int n = (nt0 + j) * 16 + lane_n;
#pragma unroll
                    for (int e = 0; e < 4; ++e) ep[(re + e) * 304 + n] = ac[j][e];
                }
            }
            __syncthreads();
            for (int cid = tid; cid < 16 * 73; cid += 256) {
                int row = cid / 73, j = cid - row * 73;
                long g = (long)(pix0 + row) * CSTR + j * 4;
                f32x4 v = *(const f32x4*)(ep + row * 304 + j * 4);
                *(f32x4*)(op + g) = v;
            }
            __syncthreads();
        }
    };

    float *X = E, *Y = D, *Z = F;
#pragma unroll 1
    for (int k = 2; k < 9; ++k) {
        LOADSC(9 + 3 * k, k, true);
        for (int job = bi; job < 800; job += RGRID)
            RUN2(job, X, Y, Z, X, B11all + (size_t)k * 97280,
                 B11all + (size_t)(9 + 2 * k) * 97280, partial, partial2);
        GBAR();
        for (int c0 = bi; c0 < 578; c0 += RGRID) {
            int q = c0 / 289, c = c0 - q * 289;
            int bnid = q ? 10 + 3 * k : 1 + k;
            fin_one(q ? partial2 : partial, bng + bnid * 289, bnbt + bnid * 289,
                    scsh, bnid, inv20, 800, c);
        }
        GBAR();
        LOADSC(10 + 3 * k, 0, false);
        float a1 = pa[1 + 2 * k];
        for (int job = bi; job < 800; job += RGRID)
            RUN1(job, 9, X, Y, B33all + (size_t)(k - 1) * 875520, a1, partial);
        GBAR();
        if (bi < 289)
            fin_one(partial, bng + (11 + 3 * k) * 289, bnbt + (11 + 3 * k) * 289,
                    scsh, 11 + 3 * k, inv20, 800, bi);
        GBAR();
        LOADSC(11 + 3 * k, 0, false);
        float a2 = pa[2 + 2 * k];
        for (int job = bi; job < 800; job += RGRID)
            RUN1(job, 1, Y, Y, B11all + (size_t)(10 + 2 * k) * 97280, a2, partial);
        GBAR();
        if (bi < 289)
            fin_one(partial, bng + (12 + 3 * k) * 289, bnbt + (12 + 3 * k) * 289,
                    scsh, 12 + 3 * k, inv20, 800, bi);
        GBAR();
        float* t = X; X = Y; Y = Z; Z = t;      // exit: X=y3, Y=idn
    }
}

// ---- final: affine(y3)+affine(idn), NHWC -> NCHW via LDS transpose ----------
__global__ void final_k(const float* __restrict__ y3, const float* __restrict__ idn,
                        float* __restrict__ out, const float* __restrict__ scshAll,
                        int bnY, int bnI) {
    __shared__ float T[32][305];
    int bi = blockIdx.x;          // 32 b x 13 hw-tiles
    int b = bi / 13, t0 = (bi - (bi / 13) * 13) * 32;
    int tid = threadIdx.x;
    int nhw = 400 - t0; if (nhw > 32) nhw = 32;
    for (int idx = tid; idx < 32 * 304; idx += 256) {
        int hwl = idx / 304, c = idx - hwl * 304;
        float v = 0.f;
        if (hwl < nhw && c < 289) {
            long pix = (long)b * 400 + t0 + hwl;
            v = scshAll[bnY * 578 + c] * y3[pix * CSTR + c] + scshAll[bnY * 578 + 289 + c]
              + scshAll[bnI * 578 + c] * idn[pix * CSTR + c] + scshAll[bnI * 578 + 289 + c];
        }
        T[hwl][c] = v;
    }
    __syncthreads();
    for (int idx = tid; idx < 289 * 32; idx += 256) {
        int c = idx >> 5, hwl = idx & 31;
        if (hwl < nhw)
            out[((long)b * 289 + c) * 400 + t0 + hwl] = T[hwl][c];
    }
}

extern "C" void kernel_launch(void* const* d_in, const int* in_sizes, int n_in,
                              void* d_out, int out_size, void* d_ws, size_t ws_size,
                              hipStream_t stream) {
    const float* x     = (const float*)d_in[0];
    const float* fW1   = (const float*)d_in[1];
    const float* fW2   = (const float*)d_in[2];
    const float* c11W1 = (const float*)d_in[4];
    const float* c11W2 = (const float*)d_in[5];
    const float* c33W1 = (const float*)d_in[7];
    const float* c33W2 = (const float*)d_in[8];
    const float* bng   = (const float*)d_in[10];
    const float* bnbt  = (const float*)d_in[11];
    const float* pa    = (const float*)d_in[12];
    float* outp = (float*)d_out;

    char* base = (char*)d_ws;
    bf16*  A    = (bf16*)base;                         // 80x80 bf16: 119,603,200 B
    bf16*  Bb   = (bf16*)(base + 119603200L);          // 40x40 bf16:  29,900,800 B
    bf16*  Cb   = (bf16*)(base + 149504000L);          // 40x40 bf16:  29,900,800 B
    float* scsh = (float*)(base + 179404800L);         // 37*578*4 =       85,544 B
    bf16*  B33s = (bf16*)(base + 179490368L);          // 1710*512*2 =  1,751,040 B
    size_t need = 181241408L;
    if (ws_size < need) return;
    float* D = (float*)base;                           // 20x20 f32 x3 (carved in A)
    float* E = (float*)(base + 14950400L);
    float* F = (float*)(base + 29900800L);
    // dead-A region reuse (A unread after y2_0 finishes):
    float* partialA = (float*)(base + 50000000L);      // 800*PST*4 = 1,856,000 B
    unsigned* bar   = (unsigned*)(base + 60000000L);   // grid-barrier counter
    bf16*  B33all   = (bf16*)(base + 100000000L);      // 8*1710*512*2 = 14,008,320 B

    // d_out doubles as scratch until final_k fully overwrites it:
    float* partial = (float*)d_out;                    // <=3200*PST*4 region
    bf16*  B11all  = (bf16*)((char*)d_out + 7424000L); // 27*190*512*2 = 5,253,120 B
    float* partial2 = partial + 800L * PST;            // second stats set
    // big-grid (6400-block) partial for the in-place y1_0 gemm: Cb is dead there
    float* partialBig = (float*)Cb;                    // 6400*PST*4 = 14,848,000 B

    const float inv80 = 1.f / 204800.f, inv40 = 1.f / 51200.f, inv20 = 1.f / 12800.f;

#define B11(cv) (B11all + (size_t)(cv) * 97280)
#define B33A(cv) (B33all + (size_t)((cv) - 1) * 875520)
#define FIN(P, bnid, invN, GN) finalize_k<<<dim3(289), dim3(256), 0, stream>>>( \
        (P), bng + (bnid) * 289, bnbt + (bnid) * 289, scsh, (bnid), (invN), (GN))

    // all 27 1x1 dense-K fragment sets, one launch
    prep11_all_k<<<dim3(27 * 190), dim3(64), 0, stream>>>(c11W1, c11W2, B11all);

    // features -> A (LDS-tiled coalesced stores + fused stats, 2048 partials)
    feat_k<<<dim3(2048), dim3(256), 0, stream>>>(x, A, fW1, fW2, partial);
    FIN(partial, 0, inv80, 2048);

    // block 0 (80 -> 40): input h0 = prelu(aff0(A))
    gemm_k<bf16, bf16, 1, false, 2><<<dim3(1600), dim3(256), 0, stream>>>(
        A, nullptr, Bb, B11(0), scsh, 0, 0, pa + 0, partial, 80, 80, 40, 40, 2);
    gemm_k<bf16, bf16, 1, false, 2><<<dim3(6400), dim3(256), 0, stream>>>(
        A, nullptr, A, B11(9), scsh, 0, 0, pa + 0, partialBig, 80, 80, 80, 80, 1);
    // merged: idn0 stats (bn 1) + y1_0 stats (bn 10)
    finalize2v_k<<<dim3(578), dim3(256), 0, stream>>>(
        partial, partialBig, bng, bnbt, scsh, 1, 10, inv40, 1600, inv80, 6400);
    prep33_k<<<dim3(1710), dim3(64), 0, stream>>>(c33W1, c33W2, B33s);
    gemm_k<bf16, bf16, 9, false, 2><<<dim3(1600), dim3(256), 0, stream>>>(
        A, nullptr, Cb, B33s, scsh, 10, 0, pa + 1, partial, 80, 80, 40, 40, 2);
    // A now dead: build all remaining 3x3 fragment sets (blocks 1..8) at once
    prep33all_k<<<dim3(3420), dim3(256), 0, stream>>>(c33W1, c33W2, B33all);
    FIN(partial, 11, inv40, 1600);                            // y2_0 -> C
    gemm_k<bf16, bf16, 1, false, 2><<<dim3(1600), dim3(256), 0, stream>>>(
        Cb, nullptr, Cb, B11(10), scsh, 11, 0, pa + 2, partial, 40, 40, 40, 40, 1);
    FIN(partial, 12, inv40, 1600);                            // y3_0 -> C (in-place)

    // block 1 (40 -> 20): input h1 = aff12(C) + aff1(B)
    gemm_k<bf16, float, 1, true, 1><<<dim3(800), dim3(256), 0, stream>>>(
        Cb, Bb, D, B11(1), scsh, 12, 1, nullptr, partialA, 40, 40, 20, 20, 2);
    gemm_k<bf16, bf16, 1, true, 2><<<dim3(1600), dim3(256), 0, stream>>>(
        Cb, Bb, Cb, B11(11), scsh, 12, 1, nullptr, partial, 40, 40, 40, 40, 1);
    // merged: idn1 stats (bn 2, partialA) + y1_1 stats (bn 13, partial)
    finalize2v_k<<<dim3(578), dim3(256), 0, stream>>>(
        partialA, partial, bng, bnbt, scsh, 2, 13, inv20, 800, inv40, 1600);
    gemm_k<bf16, float, 9, false, 2><<<dim3(400), dim3(256), 0, stream>>>(
        Cb, nullptr, E, B33A(1), scsh, 13, 0, pa + 3, partial, 40, 40, 20, 20, 2);
    FIN(partial, 14, inv20, 400);                             // y2_1 -> E
    gemm_k<float, float, 1, false, 1><<<dim3(800), dim3(256), 0, stream>>>(
        E, nullptr, E, B11(12), scsh, 14, 0, pa + 4, partial, 20, 20, 20, 20, 1);
    FIN(partial, 15, inv20, 800);                             // y3_1 -> E (in-place)

    // blocks 2..8 (20x20): ONE persistent kernel with internal grid barriers
    hipMemsetAsync(bar, 0, 64, stream);
    resid_k<<<dim3(RGRID), dim3(256), 0, stream>>>(
        E, D, F, B11all, B33all, scsh, bng, bnbt, pa, partial, partial2, bar);
    // rotation after 7 iters: (X,Y,Z) = rho^7(E,D,F) = (D,F,E) -> y3=D, idn=F
    final_k<<<dim3(416), dim3(256), 0, stream>>>(D, F, outp, scsh, 36, 9);
}

// Round 8
// 2516.711 us; speedup vs baseline: 4.4227x; 4.4227x over previous
//
#include <hip/hip_runtime.h>
#include <hip/hip_bf16.h>

#define EPS 1e-5f
#define CSTR 292        // padded channel stride (8B-aligned bf16 rows, 16B f32)
#define PST 580         // partial row stride (floats): [blk][290 sum | 290 sumsq]
#define FPIX 15         // pixels per feat_k block-tile (15*17 = 255 threads)

typedef __hip_bfloat16 bf16;
typedef short s16x8 __attribute__((ext_vector_type(8)));
typedef float f32x4 __attribute__((ext_vector_type(4)));
typedef unsigned short u16x4 __attribute__((ext_vector_type(4)));
typedef unsigned short u16x8 __attribute__((ext_vector_type(8)));

__device__ inline float bf2f(unsigned short u) {
    union { unsigned int i; float f; } z; z.i = ((unsigned int)u) << 16; return z.f;
}
__device__ inline unsigned short f2bf(float f) {
    union { bf16 h; unsigned short u; } z; z.h = __float2bfloat16(f); return z.u;
}
__device__ inline unsigned short f2bf_trunc(float f) {
    union { float f; unsigned int u; } z; z.f = f; return (unsigned short)(z.u >> 16);
}

// derive BN scale/shift for channel c from raw sums (accumulator) or scsh
__device__ inline void bn_coef(const float* scshAll, const float* gAll,
                               const float* btAll, const float* iAcc,
                               int bn, float invN, int c, float& sc, float& sh) {
    if (iAcc) {
        float m = iAcc[c] * invN;
        float v = iAcc[290 + c] * invN - m * m;
        sc = gAll[bn * 289 + c] * rsqrtf(v + EPS);
        sh = btAll[bn * 289 + c] - m * sc;
    } else {
        sc = scshAll[bn * 578 + c];
        sh = scshAll[bn * 578 + 289 + c];
    }
}

// ---- dense-kernel precompute into MFMA B-fragment order ---------------------
__device__ __forceinline__ void prep_frag(const float* w1, const float* w2,
                                          bf16* o, int kt, int nt, int l) {
#pragma unroll
    for (int e = 0; e < 8; ++e) {
        int k = kt * 32 + ((l >> 4) << 3) + e;
        int n = nt * 16 + (l & 15);
        float v = 0.f;
        if (k < 289 && n < 289)
            v = w1[(n / 17) * 17 + (k / 17)] * w2[(k % 17) * 17 + (n % 17)];
        o[e] = __float2bfloat16(v);
    }
}

__global__ void prep11_all_k(const float* __restrict__ W1all, const float* __restrict__ W2all,
                             bf16* __restrict__ Bsw) {
    int bi = blockIdx.x;                // 27*190
    int cv = bi / 190, r = bi - cv * 190;
    int kt = r / 19, nt = r - kt * 19;
    prep_frag(W1all + (size_t)cv * 289, W2all + (size_t)cv * 289,
              Bsw + (size_t)bi * 512 + threadIdx.x * 8, kt, nt, threadIdx.x);
}

__global__ void prep33_k(const float* __restrict__ W1, const float* __restrict__ W2,
                         bf16* __restrict__ Bsw) {
    int bi = blockIdx.x;                // 9*190
    int tap = bi / 190; int r = bi - tap * 190;
    int kt = r / 19, nt = r - kt * 19;
    prep_frag(W1 + (size_t)tap * 289, W2 + (size_t)tap * 289,
              Bsw + (size_t)bi * 512 + threadIdx.x * 8, kt, nt, threadIdx.x);
}

// all 3x3 fragment sets for residual blocks 1..8, one launch (into dead-A region)
__global__ void prep33all_k(const float* __restrict__ W1, const float* __restrict__ W2,
                            bf16* __restrict__ Bsw) {
    int fi = blockIdx.x * 4 + (threadIdx.x >> 6);   // 3420 blocks x 4 frags
    int l = threadIdx.x & 63;
    int kb = fi / 1710, r = fi - kb * 1710;         // kb: 0..7 -> block k=kb+1
    int tap = r / 190; int rr = r - tap * 190;
    int kt = rr / 19, nt = rr - kt * 19;
    const float* w1 = W1 + (long)(kb + 1) * 9 * 289 + (long)tap * 289;
    const float* w2 = W2 + (long)(kb + 1) * 9 * 289 + (long)tap * 289;
    prep_frag(w1, w2, Bsw + (size_t)fi * 512 + l * 8, kt, nt, l);
}

// ---- features: 3x3 s2 tensor conv, LDS-tiled stores + fused BN stats --------
__global__ __launch_bounds__(256) void feat_k(
    const float* __restrict__ x, bf16* __restrict__ out,
    const float* __restrict__ W1, const float* __restrict__ W2,
    float* __restrict__ partial) {
    __shared__ float W1s[459], W2s[153];
    __shared__ float S[289], SS[289];
    __shared__ bf16 T[FPIX][292];
    int tid = threadIdx.x;
    for (int i = tid; i < 459; i += 256) W1s[i] = W1[i];
    for (int i = tid; i < 153; i += 256) W2s[i] = W2[i];
    for (int i = tid; i < 289; i += 256) { S[i] = 0.f; SS[i] = 0.f; }
    if (tid < FPIX * 3) T[tid / 3][289 + tid % 3] = __float2bfloat16(0.f);
    int lp = tid / 17, p = tid - lp * 17;
    bool act = tid < 255;
    float sacc[17], qacc[17];
#pragma unroll
    for (int q = 0; q < 17; ++q) { sacc[q] = 0.f; qacc[q] = 0.f; }
    const int NT = (204800 + FPIX - 1) / FPIX;      // 13654
    __syncthreads();
    for (int t = blockIdx.x; t < NT; t += gridDim.x) {
        int pix0 = t * FPIX;
        int pix = pix0 + lp;
        if (act && pix < 204800) {
            int b = pix / 6400; int rr = pix - b * 6400;
            int oh = rr / 80, ow = rr - oh * 80;
            float y[17];
#pragma unroll
            for (int q = 0; q < 17; ++q) y[q] = 0.f;
            for (int di = 0; di < 3; ++di) {
                int ih = oh * 2 + di - 1;
                if (ih < 0 || ih >= 160) continue;
                for (int dj = 0; dj < 3; ++dj) {
                    int iw = ow * 2 + dj - 1;
                    if (iw < 0 || iw >= 160) continue;
                    int k = di * 3 + dj;
                    long xb = (long)b * 76800 + ih * 160 + iw;
                    float dot = W1s[(k * 17 + p) * 3 + 0] * x[xb]
                              + W1s[(k * 17 + p) * 3 + 1] * x[xb + 25600]
                              + W1s[(k * 17 + p) * 3 + 2] * x[xb + 51200];
#pragma unroll
                    for (int q = 0; q < 17; ++q) y[q] += dot * W2s[k * 17 + q];
                }
            }
#pragma unroll
            for (int q = 0; q < 17; ++q) {
                bf16 h = __float2bfloat16(y[q]);
                T[lp][p * 17 + q] = h;
                float vv = __bfloat162float(h);     // stats on rounded value
                sacc[q] += vv; qacc[q] += vv * vv;
            }
        }
        __syncthreads();
        int nv = 204800 - pix0; if (nv > FPIX) nv = FPIX;
        for (int idx = tid; idx < nv * 73; idx += 256) {
            int row = idx / 73, j = idx - row * 73;
            *(u16x4*)(out + (long)(pix0 + row) * CSTR + j * 4) =
                *(const u16x4*)(&T[row][j * 4]);
        }
        __syncthreads();
    }
    if (act) {
#pragma unroll
        for (int q = 0; q < 17; ++q) {
            atomicAdd(&S[p * 17 + q], sacc[q]);
            atomicAdd(&SS[p * 17 + q], qacc[q]);
        }
    }
    __syncthreads();
    for (int i = tid; i < 289; i += 256) {
        partial[(long)blockIdx.x * PST + i] = S[i];
        partial[(long)blockIdx.x * PST + 290 + i] = SS[i];
    }
}

// ---- MFMA GEMM conv, MROWS=16*MT, async-stage pipeline (T14) ----------------
// Stats I/O: iAcc1/iAcc2 non-null -> derive BN coef from raw atomic sums
// (tail path, no finalize launch); oAcc non-null -> atomicAdd stats out.
template <typename TI, typename TO, int TAPS, bool DUAL, int MT>
__global__ __launch_bounds__(256, MT == 2 ? 3 : 5) void gemm_k(
    const TI* __restrict__ in1, const TI* __restrict__ in2, TO* __restrict__ out,
    const bf16* __restrict__ Bs, const float* __restrict__ scshAll, int bn1, int bn2,
    const float* __restrict__ alphaPtr, float* __restrict__ partial,
    const float* __restrict__ gAll, const float* __restrict__ btAll,
    const float* __restrict__ iAcc1, const float* __restrict__ iAcc2, float invNin,
    float* __restrict__ oAcc,
    int Hin, int Win, int Hout, int Wout, int stride) {
    constexpr int MROWS = 16 * MT;
    constexpr int SITS = (37 * MROWS + 255) / 256;     // 3 (MT1) or 5 (MT2)
    static_assert(MROWS * 304 * sizeof(TO) <= 2 * MROWS * 640, "epilogue must fit As");
    __shared__ char As[2 * MROWS * 640];        // hi buffer | lo buffer
    __shared__ float sc1[296], sh1[296];
    __shared__ float sc2[DUAL ? 296 : 1], sh2[DUAL ? 296 : 1];
    __shared__ long gb00[MROWS];
    __shared__ int ihw0[MROWS];                 // (ih0+1)<<16 | (iw0+1)
    int tid = threadIdx.x;
    int HWin = Hin * Win, HWout = Hout * Wout;
    int pix0 = blockIdx.x * MROWS;
    for (int i = tid; i < 296; i += 256) {
        int cc = i < 289 ? i : 0;
        float sc, sh;
        bn_coef(scshAll, gAll, btAll, iAcc1, bn1, invNin, cc, sc, sh);
        sc1[i] = sc; sh1[i] = sh;
        if constexpr (DUAL) {
            bn_coef(scshAll, gAll, btAll, iAcc2, bn2, invNin, cc, sc, sh);
            sc2[i] = sc; sh2[i] = sh;
        }
    }
    if (tid < MROWS) {
        int op = pix0 + tid;
        int b = op / HWout; int rr = op - b * HWout;
        int oh = rr / Wout, ow = rr - oh * Wout;
        int ih0 = oh * stride + (TAPS == 9 ? -1 : 0);
        int iw0 = ow * stride + (TAPS == 9 ? -1 : 0);
        gb00[tid] = ((long)b * HWin + (long)ih0 * Win + iw0) * CSTR;
        ihw0[tid] = ((ih0 + 1) << 16) | (iw0 + 1);
    }
    if (tid < 8 * MROWS) {
        int half = tid / (4 * MROWS), r = (tid >> 2) & (MROWS - 1), c = tid & 3;
        int byte = (r * 640 + 576 + c * 16) ^ ((r & 7) << 4);
        *(u16x8*)(As + half * (MROWS * 640) + byte) = (u16x8){0, 0, 0, 0, 0, 0, 0, 0};
    }
    float alpha = DUAL ? 0.f : *alphaPtr;
    int w = tid >> 6, l = tid & 63;
    int nt0 = w * 5;
    int lane_n = l & 15;
    int kbyte = (l >> 4) << 4;
    f32x4 acc[MT][5];
#pragma unroll
    for (int m = 0; m < MT; ++m)
#pragma unroll
        for (int j = 0; j < 5; ++j) acc[m][j] = (f32x4){0.f, 0.f, 0.f, 0.f};
    __syncthreads();

    bool cact[SITS]; int cih[SITS], ciw[SITS], cwb[SITS], ck0[SITS]; long cgb[SITS];
#pragma unroll
    for (int it = 0; it < SITS; ++it) {
        int cid = it * 256 + tid;
        cact[it] = cid < 37 * MROWS;
        int row = cact[it] ? cid / 37 : 0;
        int j = cid - row * 37;
        ck0[it] = j * 8;
        cgb[it] = gb00[row] + j * 8;
        int pk = ihw0[row];
        cih[it] = (pk >> 16) - 1; ciw[it] = (pk & 0xffff) - 1;
        cwb[it] = (row * 640 + j * 16) ^ ((row & 7) << 4);
    }
    bool vld[SITS];
    u16x4 rh1[SITS][2]; f32x4 rf1[SITS][2];             // in1 raw (one used per TI)
    u16x4 rh2[DUAL ? SITS : 1][2]; f32x4 rf2[DUAL ? SITS : 1][2];

    auto LOAD = [&](int tap) {
        int di = (TAPS == 9) ? tap / 3 : 0;
        int dj = (TAPS == 9) ? tap - di * 3 : 0;
        long toff = (long)(di * Win + dj) * CSTR;
#pragma unroll
        for (int it = 0; it < SITS; ++it) {
            vld[it] = false;
            if (cact[it]) {
                int ih = cih[it] + di, iw = ciw[it] + dj;
                if (ih >= 0 && ih < Hin && iw >= 0 && iw < Win) {
                    vld[it] = true;
                    long gb = cgb[it] + toff;
                    if constexpr (sizeof(TI) == 2) {
                        rh1[it][0] = *(const u16x4*)((const bf16*)in1 + gb);
                        rh1[it][1] = *(const u16x4*)((const bf16*)in1 + gb + 4);
                        if constexpr (DUAL) {
                            rh2[it][0] = *(const u16x4*)((const bf16*)in2 + gb);
                            rh2[it][1] = *(const u16x4*)((const bf16*)in2 + gb + 4);
                        }
                    } else {
                        rf1[it][0] = *(const f32x4*)((const float*)in1 + gb);
                        rf1[it][1] = *(const f32x4*)((const float*)in1 + gb + 4);
                        if constexpr (DUAL) {
                            rf2[it][0] = *(const f32x4*)((const float*)in2 + gb);
                            rf2[it][1] = *(const f32x4*)((const float*)in2 + gb + 4);
                        }
                    }
                }
            }
        }
    };

    auto WRITE = [&]() {
#pragma unroll
        for (int it = 0; it < SITS; ++it) {
            if (!cact[it]) continue;
            float v[8];
            if (vld[it]) {
                int k0 = ck0[it];
                float r[8];
                if constexpr (sizeof(TI) == 2) {
#pragma unroll
                    for (int e = 0; e < 4; ++e) {
                        r[e] = bf2f(rh1[it][0][e]); r[4 + e] = bf2f(rh1[it][1][e]);
                    }
                } else {
#pragma unroll
                    for (int e = 0; e < 4; ++e) {
                        r[e] = rf1[it][0][e]; r[4 + e] = rf1[it][1][e];
                    }
                }
#pragma unroll
                for (int e = 0; e < 8; ++e) v[e] = sc1[k0 + e] * r[e] + sh1[k0 + e];
                if constexpr (DUAL) {
                    float q[8];
                    if constexpr (sizeof(TI) == 2) {
#pragma unroll
                        for (int e = 0; e < 4; ++e) {
                            q[e] = bf2f(rh2[it][0][e]); q[4 + e] = bf2f(rh2[it][1][e]);
                        }
                    } else {
#pragma unroll
                        for (int e = 0; e < 4; ++e) {
                            q[e] = rf2[it][0][e]; q[4 + e] = rf2[it][1][e];
                        }
                    }
#pragma unroll
                    for (int e = 0; e < 8; ++e) v[e] += sc2[k0 + e] * q[e] + sh2[k0 + e];
                } else {
#pragma unroll
                    for (int e = 0; e < 8; ++e) v[e] = v[e] >= 0.f ? v[e] : alpha * v[e];
                }
#pragma unroll
                for (int e = 0; e < 8; ++e) if (ck0[it] + e > 288) v[e] = 0.f;
            } else {
#pragma unroll
                for (int e = 0; e < 8; ++e) v[e] = 0.f;
            }
            u16x4 hi0, hi1, lo0, lo1;
#pragma unroll
            for (int e = 0; e < 4; ++e) {
                unsigned short h = f2bf(v[e]);
                hi0[e] = h; lo0[e] = f2bf_trunc(v[e] - bf2f(h));
                unsigned short h2 = f2bf(v[4 + e]);
                hi1[e] = h2; lo1[e] = f2bf_trunc(v[4 + e] - bf2f(h2));
            }
            int byte = cwb[it];
            *(u16x4*)(As + byte) = hi0;
            *(u16x4*)(As + byte + 8) = hi1;
            *(u16x4*)(As + MROWS * 640 + byte) = lo0;
            *(u16x4*)(As + MROWS * 640 + byte + 8) = lo1;
        }
    };

    LOAD(0);
#pragma unroll 1
    for (int tap = 0; tap < TAPS; ++tap) {
        WRITE();
        if (tap + 1 < TAPS) LOAD(tap + 1);      // in flight across the K-loop
        __syncthreads();
        const bf16* bp = Bs + (size_t)tap * 97280 + (size_t)l * 8;
        int swz = (lane_n & 7) << 4;
        __builtin_amdgcn_s_setprio(1);
#pragma unroll 2
        for (int kt = 0; kt < 10; ++kt) {
            s16x8 ah[MT], al[MT];
#pragma unroll
            for (int m = 0; m < MT; ++m) {
                int ro = ((m * 16 + lane_n) * 640 + kbyte + kt * 64) ^ swz;
                ah[m] = *(const s16x8*)(As + ro);
                al[m] = *(const s16x8*)(As + MROWS * 640 + ro);
            }
#pragma unroll
            for (int j = 0; j < 5; ++j) {
                if (j < 4 || w < 3) {
                    s16x8 bfr = *(const s16x8*)(bp + (size_t)(kt * 19 + nt0 + j) * 512);
#pragma unroll
                    for (int m = 0; m < MT; ++m) {
                        acc[m][j] = __builtin_amdgcn_mfma_f32_16x16x32_bf16(
                            ah[m], bfr, acc[m][j], 0, 0, 0);
                        acc[m][j] = __builtin_amdgcn_mfma_f32_16x16x32_bf16(
                            al[m], bfr, acc[m][j], 0, 0, 0);
                    }
                }
            }
        }
        __builtin_amdgcn_s_setprio(0);
        __syncthreads();
    }
    {
#pragma unroll
        for (int j = 0; j < 5; ++j) {
            float s = 0.f, ss = 0.f;
            if (j < 4 || w < 3) {
#pragma unroll
                for (int m = 0; m < MT; ++m)
#pragma unroll
                    for (int e = 0; e < 4; ++e) {
                        float v = acc[m][j][e];
                        s += v; ss += v * v;
                    }
            }
            s += __shfl_xor(s, 16); ss += __shfl_xor(ss, 16);
            s += __shfl_xor(s, 32); ss += __shfl_xor(ss, 32);
            int n = (nt0 + j) * 16 + lane_n;
            if (l < 16 && n < 289 && (j < 4 || w < 3)) {
                if (oAcc) {
                    atomicAdd(&oAcc[n], s);
                    atomicAdd(&oAcc[290 + n], ss);
                } else {
                    partial[(long)blockIdx.x * PST + n] = s;
                    partial[(long)blockIdx.x * PST + 290 + n] = ss;
                }
            }
        }
    }
    {
        TO* ep = (TO*)As;
        int re = (l >> 4) << 2;
#pragma unroll
        for (int m = 0; m < MT; ++m) {
#pragma unroll
            for (int j = 0; j < 5; ++j) {
                if (j < 4 || w < 3) {
                    int n = (nt0 + j) * 16 + lane_n;
#pragma unroll
                    for (int e = 0; e < 4; ++e) {
                        if constexpr (sizeof(TO) == 2)
                            ep[(m * 16 + re + e) * 304 + n] = __float2bfloat16(acc[m][j][e]);
                        else
                            ((float*)ep)[(m * 16 + re + e) * 304 + n] = acc[m][j][e];
                    }
                }
            }
        }
        __syncthreads();
        for (int cid = tid; cid < MROWS * 73; cid += 256) {
            int row = cid / 73, j = cid - row * 73;
            long g = (long)(pix0 + row) * CSTR + j * 4;
            if constexpr (sizeof(TO) == 2) {
                u16x4 v = *(const u16x4*)((const bf16*)ep + row * 304 + j * 4);
                *(u16x4*)((bf16*)out + g) = v;
            } else {
                f32x4 v = *(const f32x4*)((const float*)ep + row * 304 + j * 4);
                *(f32x4*)((float*)out + g) = v;
            }
        }
    }
}

// ---- merged idn+y1 kernel: blocks 2..8, 20x20 stride-1, accum stats I/O -----
__global__ __launch_bounds__(256, 3) void gemm2_k(
    const float* __restrict__ in1, const float* __restrict__ in2,
    float* __restrict__ out1, float* __restrict__ out2,
    const bf16* __restrict__ Bs1, const bf16* __restrict__ Bs2,
    const float* __restrict__ scshAll, int bn1, int bn2,
    const float* __restrict__ gAll, const float* __restrict__ btAll,
    const float* __restrict__ iAcc1, const float* __restrict__ iAcc2, float invNin,
    float* __restrict__ oAcc1, float* __restrict__ oAcc2) {
    constexpr int MROWS = 16;
    __shared__ char As[2 * MROWS * 640];
    __shared__ float sc1[296], sh1[296], sc2[296], sh2[296];
    int tid = threadIdx.x;
    for (int i = tid; i < 296; i += 256) {
        int cc = i < 289 ? i : 0;
        float sc, sh;
        bn_coef(scshAll, gAll, btAll, iAcc1, bn1, invNin, cc, sc, sh);
        sc1[i] = sc; sh1[i] = sh;
        bn_coef(scshAll, gAll, btAll, iAcc2, bn2, invNin, cc, sc, sh);
        sc2[i] = sc; sh2[i] = sh;
    }
    if (tid < 128) {
        int half = tid >> 6, r = (tid >> 2) & 15, c = tid & 3;
        int byte = (r * 640 + 576 + c * 16) ^ ((r & 7) << 4);
        *(u16x8*)(As + half * (MROWS * 640) + byte) = (u16x8){0, 0, 0, 0, 0, 0, 0, 0};
    }
    int pix0 = blockIdx.x * MROWS;
    int w = tid >> 6, l = tid & 63;
    int nt0 = w * 5, lane_n = l & 15, kbyte = (l >> 4) << 4;
    f32x4 acc1[5], acc2[5];
#pragma unroll
    for (int j = 0; j < 5; ++j) {
        acc1[j] = (f32x4){0.f, 0.f, 0.f, 0.f};
        acc2[j] = (f32x4){0.f, 0.f, 0.f, 0.f};
    }
    __syncthreads();
#pragma unroll
    for (int it = 0; it < 3; ++it) {
        int cid = it * 256 + tid;
        if (cid < 592) {
            int row = cid / 37, j = cid - row * 37, k0 = j * 8;
            long gb = (long)(pix0 + row) * CSTR + k0;
            f32x4 a = *(const f32x4*)(in1 + gb), b = *(const f32x4*)(in1 + gb + 4);
            f32x4 c = *(const f32x4*)(in2 + gb), d = *(const f32x4*)(in2 + gb + 4);
            float v[8];
#pragma unroll
            for (int e = 0; e < 4; ++e) {
                v[e] = sc1[k0 + e] * a[e] + sh1[k0 + e] + sc2[k0 + e] * c[e] + sh2[k0 + e];
                v[4 + e] = sc1[k0 + 4 + e] * b[e] + sh1[k0 + 4 + e]
                         + sc2[k0 + 4 + e] * d[e] + sh2[k0 + 4 + e];
            }
#pragma unroll
            for (int e = 0; e < 8; ++e) if (k0 + e > 288) v[e] = 0.f;
            u16x4 hi0, hi1, lo0, lo1;
#pragma unroll
            for (int e = 0; e < 4; ++e) {
                unsigned short h = f2bf(v[e]);
                hi0[e] = h; lo0[e] = f2bf_trunc(v[e] - bf2f(h));
                unsigned short h2 = f2bf(v[4 + e]);
                hi1[e] = h2; lo1[e] = f2bf_trunc(v[4 + e] - bf2f(h2));
            }
            int byte = (row * 640 + j * 16) ^ ((row & 7) << 4);
            *(u16x4*)(As + byte) = hi0;
            *(u16x4*)(As + byte + 8) = hi1;
            *(u16x4*)(As + MROWS * 640 + byte) = lo0;
            *(u16x4*)(As + MROWS * 640 + byte + 8) = lo1;
        }
    }
    __syncthreads();
    const bf16* bp1 = Bs1 + (size_t)l * 8;
    const bf16* bp2 = Bs2 + (size_t)l * 8;
    int swz = (lane_n & 7) << 4;
    __builtin_amdgcn_s_setprio(1);
#pragma unroll 2
    for (int kt = 0; kt < 10; ++kt) {
        int ro = (lane_n * 640 + kbyte + kt * 64) ^ swz;
        s16x8 ah = *(const s16x8*)(As + ro);
        s16x8 al = *(const s16x8*)(As + MROWS * 640 + ro);
#pragma unroll
        for (int j = 0; j < 5; ++j) {
            if (j < 4 || w < 3) {
                size_t fo = (size_t)(kt * 19 + nt0 + j) * 512;
                s16x8 b1 = *(const s16x8*)(bp1 + fo);
                acc1[j] = __builtin_amdgcn_mfma_f32_16x16x32_bf16(ah, b1, acc1[j], 0, 0, 0);
                acc1[j] = __builtin_amdgcn_mfma_f32_16x16x32_bf16(al, b1, acc1[j], 0, 0, 0);
                s16x8 b2 = *(const s16x8*)(bp2 + fo);
                acc2[j] = __builtin_amdgcn_mfma_f32_16x16x32_bf16(ah, b2, acc2[j], 0, 0, 0);
                acc2[j] = __builtin_amdgcn_mfma_f32_16x16x32_bf16(al, b2, acc2[j], 0, 0, 0);
            }
        }
    }
    __builtin_amdgcn_s_setprio(0);
    __syncthreads();
#pragma unroll
    for (int j = 0; j < 5; ++j) {
        float s1 = 0.f, q1 = 0.f, s2 = 0.f, q2 = 0.f;
        if (j < 4 || w < 3) {
#pragma unroll
            for (int e = 0; e < 4; ++e) {
                float v1 = acc1[j][e]; s1 += v1; q1 += v1 * v1;
                float v2 = acc2[j][e]; s2 += v2; q2 += v2 * v2;
            }
        }
        s1 += __shfl_xor(s1, 16); q1 += __shfl_xor(q1, 16);
        s1 += __shfl_xor(s1, 32); q1 += __shfl_xor(q1, 32);
        s2 += __shfl_xor(s2, 16); q2 += __shfl_xor(q2, 16);
        s2 += __shfl_xor(s2, 32); q2 += __shfl_xor(q2, 32);
        int n = (nt0 + j) * 16 + lane_n;
        if (l < 16 && n < 289 && (j < 4 || w < 3)) {
            atomicAdd(&oAcc1[n], s1); atomicAdd(&oAcc1[290 + n], q1);
            atomicAdd(&oAcc2[n], s2); atomicAdd(&oAcc2[290 + n], q2);
        }
    }
    float* ep = (float*)As;
    int re = (l >> 4) << 2;
#pragma unroll
    for (int pass = 0; pass < 2; ++pass) {
        const f32x4* ac = pass ? acc2 : acc1;
        float* op = pass ? out2 : out1;
#pragma unroll
        for (int j = 0; j < 5; ++j) {
            if (j < 4 || w < 3) {
                int n = (nt0 + j) * 16 + lane_n;
#pragma unroll
                for (int e = 0; e < 4; ++e) ep[(re + e) * 304 + n] = ac[j][e];
            }
        }
        __syncthreads();
        for (int cid = tid; cid < MROWS * 73; cid += 256) {
            int row = cid / 73, j = cid - row * 73;
            long g = (long)(pix0 + row) * CSTR + j * 4;
            f32x4 v = *(const f32x4*)(ep + row * 304 + j * 4);
            *(f32x4*)(op + g) = v;
        }
        __syncthreads();
    }
}

__device__ __forceinline__ void fin_one(const float* partial, const float* g,
                                        const float* bt, float* scshAll,
                                        int bnid, float invN, int GN, int c) {
    float s = 0.f, ss = 0.f;
    for (int k = threadIdx.x; k < GN; k += 256) {
        s += partial[(long)k * PST + c];
        ss += partial[(long)k * PST + 290 + c];
    }
    for (int o = 32; o; o >>= 1) { s += __shfl_down(s, o); ss += __shfl_down(ss, o); }
    __shared__ float ls[4], lss[4];
    int w = threadIdx.x >> 6;
    if ((threadIdx.x & 63) == 0) { ls[w] = s; lss[w] = ss; }
    __syncthreads();
    if (threadIdx.x == 0) {
        s = ls[0] + ls[1] + ls[2] + ls[3];
        ss = lss[0] + lss[1] + lss[2] + lss[3];
        float m = s * invN;
        float v = ss * invN - m * m;
        float sc = g[c] * rsqrtf(v + EPS);
        scshAll[bnid * 578 + c] = sc;
        scshAll[bnid * 578 + 289 + c] = bt[c] - m * sc;
    }
}

__global__ void finalize_k(const float* __restrict__ partial, const float* __restrict__ g,
                           const float* __restrict__ bt, float* __restrict__ scshAll,
                           int bnid, float invN, int GN) {
    fin_one(partial, g, bt, scshAll, bnid, invN, GN, blockIdx.x);
}

// two independent stats sets (possibly different partials / GN / invN)
__global__ void finalize2v_k(const float* __restrict__ pA, const float* __restrict__ pB,
                             const float* __restrict__ gAll, const float* __restrict__ btAll,
                             float* __restrict__ scshAll, int bnA, int bnB,
                             float invA, int GNa, float invB, int GNb) {
    int q = blockIdx.x / 289, c = blockIdx.x - q * 289;
    const float* p = q ? pB : pA;
    int bnid = q ? bnB : bnA;
    fin_one(p, gAll + bnid * 289, btAll + bnid * 289, scshAll, bnid,
            q ? invB : invA, q ? GNb : GNa, c);
}

// ---- final: affine(y3)+affine(idn) from raw accums, NHWC -> NCHW ------------
__global__ void final_k(const float* __restrict__ y3, const float* __restrict__ idn,
                        float* __restrict__ out,
                        const float* __restrict__ gAll, const float* __restrict__ btAll,
                        const float* __restrict__ iAccY, const float* __restrict__ iAccI,
                        int bnY, int bnI, float invN) {
    __shared__ float T[32][305];
    __shared__ float scY[289], shY[289], scI[289], shI[289];
    int tid = threadIdx.x;
    for (int i = tid; i < 289; i += 256) {
        float sc, sh;
        bn_coef(nullptr, gAll, btAll, iAccY, bnY, invN, i, sc, sh);
        scY[i] = sc; shY[i] = sh;
        bn_coef(nullptr, gAll, btAll, iAccI, bnI, invN, i, sc, sh);
        scI[i] = sc; shI[i] = sh;
    }
    __syncthreads();
    int bi = blockIdx.x;          // 32 b x 13 hw-tiles
    int b = bi / 13, t0 = (bi - (bi / 13) * 13) * 32;
    int nhw = 400 - t0; if (nhw > 32) nhw = 32;
    for (int idx = tid; idx < 32 * 304; idx += 256) {
        int hwl = idx / 304, c = idx - hwl * 304;
        float v = 0.f;
        if (hwl < nhw && c < 289) {
            long pix = (long)b * 400 + t0 + hwl;
            v = scY[c] * y3[pix * CSTR + c] + shY[c]
              + scI[c] * idn[pix * CSTR + c] + shI[c];
        }
        T[hwl][c] = v;
    }
    __syncthreads();
    for (int idx = tid; idx < 289 * 32; idx += 256) {
        int c = idx >> 5, hwl = idx & 31;
        if (hwl < nhw)
            out[((long)b * 289 + c) * 400 + t0 + hwl] = T[hwl][c];
    }
}

extern "C" void kernel_launch(void* const* d_in, const int* in_sizes, int n_in,
                              void* d_out, int out_size, void* d_ws, size_t ws_size,
                              hipStream_t stream) {
    const float* x     = (const float*)d_in[0];
    const float* fW1   = (const float*)d_in[1];
    const float* fW2   = (const float*)d_in[2];
    const float* c11W1 = (const float*)d_in[4];
    const float* c11W2 = (const float*)d_in[5];
    const float* c33W1 = (const float*)d_in[7];
    const float* c33W2 = (const float*)d_in[8];
    const float* bng   = (const float*)d_in[10];
    const float* bnbt  = (const float*)d_in[11];
    const float* pa    = (const float*)d_in[12];
    float* outp = (float*)d_out;

    char* base = (char*)d_ws;
    bf16*  A    = (bf16*)base;                         // 80x80 bf16: 119,603,200 B
    bf16*  Bb   = (bf16*)(base + 119603200L);          // 40x40 bf16:  29,900,800 B
    bf16*  Cb   = (bf16*)(base + 149504000L);          // 40x40 bf16:  29,900,800 B
    float* scsh = (float*)(base + 179404800L);         // 37*578*4 =       85,544 B
    bf16*  B33s = (bf16*)(base + 179490368L);          // 1710*512*2 =  1,751,040 B
    size_t need = 181241408L;
    if (ws_size < need) return;
    float* D = (float*)base;                           // 20x20 f32 x3 (carved in A)
    float* E = (float*)(base + 14950400L);
    float* F = (float*)(base + 29900800L);
    // dead-A region reuse (A unread after y2_0 finishes):
    float* partialA = (float*)(base + 50000000L);      // 800*PST*4 = 1,856,000 B
    float* accT     = (float*)(base + 60000000L);      // 30*580*4 = 69,600 B
    bf16*  B33all   = (bf16*)(base + 100000000L);      // 8*1710*512*2 = 14,008,320 B

    // d_out doubles as scratch until final_k fully overwrites it:
    float* partial = (float*)d_out;                    // <=6400*PST*4 region
    bf16*  B11all  = (bf16*)((char*)d_out + 7424000L); // 27*190*512*2 = 5,253,120 B
    // big-grid (6400-block) partial for the in-place y1_0 gemm: Cb is dead there
    float* partialBig = (float*)Cb;                    // 6400*PST*4 = 14,848,000 B

    const float inv80 = 1.f / 204800.f, inv40 = 1.f / 51200.f, inv20 = 1.f / 12800.f;

#define B11(cv) (B11all + (size_t)(cv) * 97280)
#define B33A(cv) (B33all + (size_t)((cv) - 1) * 875520)
#define ACC(s) (accT + (s) * 580)
#define ACCK(ki, j) (accT + (2 + (ki) * 4 + (j)) * 580)
#define NOACC bng, bnbt, nullptr, nullptr, 0.f, nullptr
#define FIN(P, bnid, invN, GN) finalize_k<<<dim3(289), dim3(256), 0, stream>>>( \
        (P), bng + (bnid) * 289, bnbt + (bnid) * 289, scsh, (bnid), (invN), (GN))

    // all 27 1x1 dense-K fragment sets, one launch
    prep11_all_k<<<dim3(27 * 190), dim3(64), 0, stream>>>(c11W1, c11W2, B11all);

    // features -> A (LDS-tiled coalesced stores + fused stats, 2048 partials)
    feat_k<<<dim3(2048), dim3(256), 0, stream>>>(x, A, fW1, fW2, partial);
    FIN(partial, 0, inv80, 2048);

    // block 0 (80 -> 40): input h0 = prelu(aff0(A))
    gemm_k<bf16, bf16, 1, false, 2><<<dim3(1600), dim3(256), 0, stream>>>(
        A, nullptr, Bb, B11(0), scsh, 0, 0, pa + 0, partial, NOACC,
        80, 80, 40, 40, 2);
    gemm_k<bf16, bf16, 1, false, 2><<<dim3(6400), dim3(256), 0, stream>>>(
        A, nullptr, A, B11(9), scsh, 0, 0, pa + 0, partialBig, NOACC,
        80, 80, 80, 80, 1);
    // merged: idn0 stats (bn 1) + y1_0 stats (bn 10)
    finalize2v_k<<<dim3(578), dim3(256), 0, stream>>>(
        partial, partialBig, bng, bnbt, scsh, 1, 10, inv40, 1600, inv80, 6400);
    prep33_k<<<dim3(1710), dim3(64), 0, stream>>>(c33W1, c33W2, B33s);
    gemm_k<bf16, bf16, 9, false, 2><<<dim3(1600), dim3(256), 0, stream>>>(
        A, nullptr, Cb, B33s, scsh, 10, 0, pa + 1, partial, NOACC,
        80, 80, 40, 40, 2);
    // A now dead: build all remaining 3x3 fragment sets (blocks 1..8) at once,
    // and zero the tail stats accumulators (one memset covers all 30).
    prep33all_k<<<dim3(3420), dim3(256), 0, stream>>>(c33W1, c33W2, B33all);
    hipMemsetAsync(accT, 0, 30 * 580 * sizeof(float), stream);
    FIN(partial, 11, inv40, 1600);                            // y2_0 -> C
    gemm_k<bf16, bf16, 1, false, 2><<<dim3(1600), dim3(256), 0, stream>>>(
        Cb, nullptr, Cb, B11(10), scsh, 11, 0, pa + 2, partial, NOACC,
        40, 40, 40, 40, 1);
    FIN(partial, 12, inv40, 1600);                            // y3_0 -> C (in-place)

    // block 1 (40 -> 20): input h1 = aff12(C) + aff1(B)
    gemm_k<bf16, float, 1, true, 1><<<dim3(800), dim3(256), 0, stream>>>(
        Cb, Bb, D, B11(1), scsh, 12, 1, nullptr, partialA, NOACC,
        40, 40, 20, 20, 2);
    gemm_k<bf16, bf16, 1, true, 2><<<dim3(1600), dim3(256), 0, stream>>>(
        Cb, Bb, Cb, B11(11), scsh, 12, 1, nullptr, partial, NOACC,
        40, 40, 40, 40, 1);
    // merged: idn1 stats (bn 2, partialA) + y1_1 stats (bn 13, partial)
    finalize2v_k<<<dim3(578), dim3(256), 0, stream>>>(
        partialA, partial, bng, bnbt, scsh, 2, 13, inv20, 800, inv40, 1600);
    // y2_1: scsh input (bn13), accum output ACC(0) -> no FIN needed
    gemm_k<bf16, float, 9, false, 2><<<dim3(400), dim3(256), 0, stream>>>(
        Cb, nullptr, E, B33A(1), scsh, 13, 0, pa + 3, partial,
        bng, bnbt, nullptr, nullptr, 0.f, ACC(0), 40, 40, 20, 20, 2);
    // y3_1: accum input ACC(0) (bn14), accum output ACC(1)
    gemm_k<float, float, 1, false, 1><<<dim3(800), dim3(256), 0, stream>>>(
        E, nullptr, E, B11(12), scsh, 14, 0, pa + 4, partial,
        bng, bnbt, ACC(0), nullptr, inv20, ACC(1), 20, 20, 20, 20, 1);

    // blocks 2..8 (20x20): 3 launches per block, stats via atomic accums
    float *X = E, *Y = D, *Z = F;
    for (int k = 2; k < 9; ++k) {
        int ki = k - 2;
        const float* iA1 = (k == 2) ? ACC(1) : ACCK(ki - 1, 3);   // y3_{k-1} (bn 9+3k)
        const float* iA2 = (k == 2) ? nullptr : ACCK(ki - 1, 0);  // idn_{k-1} (bn k)
        gemm2_k<<<dim3(800), dim3(256), 0, stream>>>(
            X, Y, Z, X, B11(k), B11(9 + 2 * k), scsh, 9 + 3 * k, k,
            bng, bnbt, iA1, iA2, inv20, ACCK(ki, 0), ACCK(ki, 1));
        gemm_k<float, float, 9, false, 2><<<dim3(400), dim3(256), 0, stream>>>(
            X, nullptr, Y, B33A(k), scsh, 10 + 3 * k, 0, pa + 1 + 2 * k, partial,
            bng, bnbt, ACCK(ki, 1), nullptr, inv20, ACCK(ki, 2), 20, 20, 20, 20, 1);
        gemm_k<float, float, 1, false, 1><<<dim3(800), dim3(256), 0, stream>>>(
            Y, nullptr, Y, B11(10 + 2 * k), scsh, 11 + 3 * k, 0, pa + 2 + 2 * k, partial,
            bng, bnbt, ACCK(ki, 2), nullptr, inv20, ACCK(ki, 3), 20, 20, 20, 20, 1);
        float* t = X; X = Y; Y = Z; Z = t;                    // exit: X=y3, Y=idn
    }
    // final: y3_8 coef from ACCK(6,3) (bn36), idn_8 coef from ACCK(6,0) (bn9)
    final_k<<<dim3(416), dim3(256), 0, stream>>>(
        X, Y, outp, bng, bnbt, ACCK(6, 3), ACCK(6, 0), 36, 9, inv20);
}

// Round 9
// 1889.340 us; speedup vs baseline: 5.8913x; 1.3321x over previous
//
#include <hip/hip_runtime.h>
#include <hip/hip_bf16.h>

#define EPS 1e-5f
#define CSTR 292        // padded channel stride (8B-aligned bf16 rows, 16B f32)
#define PST 580         // partial row stride (floats): [blk][290 sum | 290 sumsq]
#define FPIX 15         // pixels per feat_k block-tile (15*17 = 255 threads)

typedef __hip_bfloat16 bf16;
typedef short s16x8 __attribute__((ext_vector_type(8)));
typedef float f32x4 __attribute__((ext_vector_type(4)));
typedef unsigned short u16x4 __attribute__((ext_vector_type(4)));
typedef unsigned short u16x8 __attribute__((ext_vector_type(8)));

__device__ inline float bf2f(unsigned short u) {
    union { unsigned int i; float f; } z; z.i = ((unsigned int)u) << 16; return z.f;
}
__device__ inline unsigned short f2bf(float f) {
    union { bf16 h; unsigned short u; } z; z.h = __float2bfloat16(f); return z.u;
}
__device__ inline unsigned short f2bf_trunc(float f) {
    union { float f; unsigned int u; } z; z.f = f; return (unsigned short)(z.u >> 16);
}
// bijective chunked XCD swizzle: contiguous block ranges per XCD (needs n%8==0)
__device__ inline int xcd_swz(int b, int n) {
    return ((n & 7) == 0) ? ((b & 7) * (n >> 3) + (b >> 3)) : b;
}

// ---- dense-kernel precompute into MFMA B-fragment order ---------------------
__device__ __forceinline__ void prep_frag(const float* w1, const float* w2,
                                          bf16* o, int kt, int nt, int l) {
#pragma unroll
    for (int e = 0; e < 8; ++e) {
        int k = kt * 32 + ((l >> 4) << 3) + e;
        int n = nt * 16 + (l & 15);
        float v = 0.f;
        if (k < 289 && n < 289)
            v = w1[(n / 17) * 17 + (k / 17)] * w2[(k % 17) * 17 + (n % 17)];
        o[e] = __float2bfloat16(v);
    }
}

__global__ void prep11_all_k(const float* __restrict__ W1all, const float* __restrict__ W2all,
                             bf16* __restrict__ Bsw) {
    int bi = blockIdx.x;                // 27*190
    int cv = bi / 190, r = bi - cv * 190;
    int kt = r / 19, nt = r - kt * 19;
    prep_frag(W1all + (size_t)cv * 289, W2all + (size_t)cv * 289,
              Bsw + (size_t)bi * 512 + threadIdx.x * 8, kt, nt, threadIdx.x);
}

__global__ void prep33_k(const float* __restrict__ W1, const float* __restrict__ W2,
                         bf16* __restrict__ Bsw) {
    int bi = blockIdx.x;                // 9*190
    int tap = bi / 190; int r = bi - tap * 190;
    int kt = r / 19, nt = r - kt * 19;
    prep_frag(W1 + (size_t)tap * 289, W2 + (size_t)tap * 289,
              Bsw + (size_t)bi * 512 + threadIdx.x * 8, kt, nt, threadIdx.x);
}

// all 3x3 fragment sets for residual blocks 1..8, one launch (into dead-A region)
__global__ void prep33all_k(const float* __restrict__ W1, const float* __restrict__ W2,
                            bf16* __restrict__ Bsw) {
    int fi = blockIdx.x * 4 + (threadIdx.x >> 6);   // 3420 blocks x 4 frags
    int l = threadIdx.x & 63;
    int kb = fi / 1710, r = fi - kb * 1710;         // kb: 0..7 -> block k=kb+1
    int tap = r / 190; int rr = r - tap * 190;
    int kt = rr / 19, nt = rr - kt * 19;
    const float* w1 = W1 + (long)(kb + 1) * 9 * 289 + (long)tap * 289;
    const float* w2 = W2 + (long)(kb + 1) * 9 * 289 + (long)tap * 289;
    prep_frag(w1, w2, Bsw + (size_t)fi * 512 + l * 8, kt, nt, l);
}

// ---- features: 3x3 s2 tensor conv, LDS-tiled stores + fused BN stats --------
__global__ __launch_bounds__(256) void feat_k(
    const float* __restrict__ x, bf16* __restrict__ out,
    const float* __restrict__ W1, const float* __restrict__ W2,
    float* __restrict__ partial) {
    __shared__ float W1s[459], W2s[153];
    __shared__ float S[289], SS[289];
    __shared__ bf16 T[FPIX][292];
    int tid = threadIdx.x;
    for (int i = tid; i < 459; i += 256) W1s[i] = W1[i];
    for (int i = tid; i < 153; i += 256) W2s[i] = W2[i];
    for (int i = tid; i < 289; i += 256) { S[i] = 0.f; SS[i] = 0.f; }
    if (tid < FPIX * 3) T[tid / 3][289 + tid % 3] = __float2bfloat16(0.f);
    int lp = tid / 17, p = tid - lp * 17;
    bool act = tid < 255;
    float sacc[17], qacc[17];
#pragma unroll
    for (int q = 0; q < 17; ++q) { sacc[q] = 0.f; qacc[q] = 0.f; }
    const int NT = (204800 + FPIX - 1) / FPIX;      // 13654
    __syncthreads();
    for (int t = blockIdx.x; t < NT; t += gridDim.x) {
        int pix0 = t * FPIX;
        int pix = pix0 + lp;
        if (act && pix < 204800) {
            int b = pix / 6400; int rr = pix - b * 6400;
            int oh = rr / 80, ow = rr - oh * 80;
            float y[17];
#pragma unroll
            for (int q = 0; q < 17; ++q) y[q] = 0.f;
            for (int di = 0; di < 3; ++di) {
                int ih = oh * 2 + di - 1;
                if (ih < 0 || ih >= 160) continue;
                for (int dj = 0; dj < 3; ++dj) {
                    int iw = ow * 2 + dj - 1;
                    if (iw < 0 || iw >= 160) continue;
                    int k = di * 3 + dj;
                    long xb = (long)b * 76800 + ih * 160 + iw;
                    float dot = W1s[(k * 17 + p) * 3 + 0] * x[xb]
                              + W1s[(k * 17 + p) * 3 + 1] * x[xb + 25600]
                              + W1s[(k * 17 + p) * 3 + 2] * x[xb + 51200];
#pragma unroll
                    for (int q = 0; q < 17; ++q) y[q] += dot * W2s[k * 17 + q];
                }
            }
#pragma unroll
            for (int q = 0; q < 17; ++q) {
                bf16 h = __float2bfloat16(y[q]);
                T[lp][p * 17 + q] = h;
                float vv = __bfloat162float(h);     // stats on rounded value
                sacc[q] += vv; qacc[q] += vv * vv;
            }
        }
        __syncthreads();
        int nv = 204800 - pix0; if (nv > FPIX) nv = FPIX;
        for (int idx = tid; idx < nv * 73; idx += 256) {
            int row = idx / 73, j = idx - row * 73;
            *(u16x4*)(out + (long)(pix0 + row) * CSTR + j * 4) =
                *(const u16x4*)(&T[row][j * 4]);
        }
        __syncthreads();
    }
    if (act) {
#pragma unroll
        for (int q = 0; q < 17; ++q) {
            atomicAdd(&S[p * 17 + q], sacc[q]);
            atomicAdd(&SS[p * 17 + q], qacc[q]);
        }
    }
    __syncthreads();
    for (int i = tid; i < 289; i += 256) {
        partial[(long)blockIdx.x * PST + i] = S[i];
        partial[(long)blockIdx.x * PST + 290 + i] = SS[i];
    }
}

// ---- MFMA GEMM conv, MROWS=16*MT, async-stage pipeline (T14) ----------------
// Split-precision A (hi/lo bf16 -> ~fp32 A). Wave-nt-split (4x B reuse).
// MT=2 (MROWS=32) for all TAPS=9 and big-grid TAPS=1 (halves B L2 traffic);
// MT=1 for small TAPS=1 kernels. XCD-chunked block swizzle for L2 locality.
template <typename TI, typename TO, int TAPS, bool DUAL, int MT>
__global__ __launch_bounds__(256, MT == 2 ? 3 : 5) void gemm_k(
    const TI* __restrict__ in1, const TI* __restrict__ in2, TO* __restrict__ out,
    const bf16* __restrict__ Bs, const float* __restrict__ scshAll, int bn1, int bn2,
    const float* __restrict__ alphaPtr, float* __restrict__ partial,
    int Hin, int Win, int Hout, int Wout, int stride) {
    constexpr int MROWS = 16 * MT;
    constexpr int SITS = (37 * MROWS + 255) / 256;     // 3 (MT1) or 5 (MT2)
    static_assert(MROWS * 304 * sizeof(TO) <= 2 * MROWS * 640, "epilogue must fit As");
    __shared__ char As[2 * MROWS * 640];        // hi buffer | lo buffer
    __shared__ float sc1[296], sh1[296];
    __shared__ float sc2[DUAL ? 296 : 1], sh2[DUAL ? 296 : 1];
    __shared__ long gb00[MROWS];
    __shared__ int ihw0[MROWS];                 // (ih0+1)<<16 | (iw0+1)
    int tid = threadIdx.x;
    int HWin = Hin * Win, HWout = Hout * Wout;
    int bid = xcd_swz(blockIdx.x, gridDim.x);
    int pix0 = bid * MROWS;
    for (int i = tid; i < 296; i += 256) {
        int cc = i < 289 ? i : 0;
        sc1[i] = scshAll[bn1 * 578 + cc]; sh1[i] = scshAll[bn1 * 578 + 289 + cc];
        if constexpr (DUAL) {
            sc2[i] = scshAll[bn2 * 578 + cc]; sh2[i] = scshAll[bn2 * 578 + 289 + cc];
        }
    }
    if (tid < MROWS) {
        int op = pix0 + tid;
        int b = op / HWout; int rr = op - b * HWout;
        int oh = rr / Wout, ow = rr - oh * Wout;
        int ih0 = oh * stride + (TAPS == 9 ? -1 : 0);
        int iw0 = ow * stride + (TAPS == 9 ? -1 : 0);
        gb00[tid] = ((long)b * HWin + (long)ih0 * Win + iw0) * CSTR;
        ihw0[tid] = ((ih0 + 1) << 16) | (iw0 + 1);
    }
    // zero never-staged LDS tail (bytes [592,640) per row, both halves; the
    // [576,592) chunk is overwritten by staging). Garbage must not reach MFMA.
    if (tid < 8 * MROWS) {
        int half = tid / (4 * MROWS), r = (tid >> 2) & (MROWS - 1), c = tid & 3;
        int byte = (r * 640 + 576 + c * 16) ^ ((r & 7) << 4);
        *(u16x8*)(As + half * (MROWS * 640) + byte) = (u16x8){0, 0, 0, 0, 0, 0, 0, 0};
    }
    float alpha = DUAL ? 0.f : *alphaPtr;
    int w = tid >> 6, l = tid & 63;
    int nt0 = w * 5;
    int lane_n = l & 15;
    int kbyte = (l >> 4) << 4;
    f32x4 acc[MT][5];
#pragma unroll
    for (int m = 0; m < MT; ++m)
#pragma unroll
        for (int j = 0; j < 5; ++j) acc[m][j] = (f32x4){0.f, 0.f, 0.f, 0.f};
    __syncthreads();

    bool cact[SITS]; int cih[SITS], ciw[SITS], cwb[SITS], ck0[SITS]; long cgb[SITS];
#pragma unroll
    for (int it = 0; it < SITS; ++it) {
        int cid = it * 256 + tid;
        cact[it] = cid < 37 * MROWS;
        int row = cact[it] ? cid / 37 : 0;
        int j = cid - row * 37;
        ck0[it] = j * 8;
        cgb[it] = gb00[row] + j * 8;
        int pk = ihw0[row];
        cih[it] = (pk >> 16) - 1; ciw[it] = (pk & 0xffff) - 1;
        cwb[it] = (row * 640 + j * 16) ^ ((row & 7) << 4);
    }
    bool vld[SITS];
    u16x4 rh1[SITS][2]; f32x4 rf1[SITS][2];             // in1 raw (one used per TI)
    u16x4 rh2[DUAL ? SITS : 1][2]; f32x4 rf2[DUAL ? SITS : 1][2];

    auto LOAD = [&](int tap) {
        int di = (TAPS == 9) ? tap / 3 : 0;
        int dj = (TAPS == 9) ? tap - di * 3 : 0;
        long toff = (long)(di * Win + dj) * CSTR;
#pragma unroll
        for (int it = 0; it < SITS; ++it) {
            vld[it] = false;
            if (cact[it]) {
                int ih = cih[it] + di, iw = ciw[it] + dj;
                if (ih >= 0 && ih < Hin && iw >= 0 && iw < Win) {
                    vld[it] = true;
                    long gb = cgb[it] + toff;
                    if constexpr (sizeof(TI) == 2) {
                        rh1[it][0] = *(const u16x4*)((const bf16*)in1 + gb);
                        rh1[it][1] = *(const u16x4*)((const bf16*)in1 + gb + 4);
                        if constexpr (DUAL) {
                            rh2[it][0] = *(const u16x4*)((const bf16*)in2 + gb);
                            rh2[it][1] = *(const u16x4*)((const bf16*)in2 + gb + 4);
                        }
                    } else {
                        rf1[it][0] = *(const f32x4*)((const float*)in1 + gb);
                        rf1[it][1] = *(const f32x4*)((const float*)in1 + gb + 4);
                        if constexpr (DUAL) {
                            rf2[it][0] = *(const f32x4*)((const float*)in2 + gb);
                            rf2[it][1] = *(const f32x4*)((const float*)in2 + gb + 4);
                        }
                    }
                }
            }
        }
    };

    auto WRITE = [&]() {
#pragma unroll
        for (int it = 0; it < SITS; ++it) {
            if (!cact[it]) continue;
            float v[8];
            if (vld[it]) {
                int k0 = ck0[it];
                float r[8];
                if constexpr (sizeof(TI) == 2) {
#pragma unroll
                    for (int e = 0; e < 4; ++e) {
                        r[e] = bf2f(rh1[it][0][e]); r[4 + e] = bf2f(rh1[it][1][e]);
                    }
                } else {
#pragma unroll
                    for (int e = 0; e < 4; ++e) {
                        r[e] = rf1[it][0][e]; r[4 + e] = rf1[it][1][e];
                    }
                }
#pragma unroll
                for (int e = 0; e < 8; ++e) v[e] = sc1[k0 + e] * r[e] + sh1[k0 + e];
                if constexpr (DUAL) {
                    float q[8];
                    if constexpr (sizeof(TI) == 2) {
#pragma unroll
                        for (int e = 0; e < 4; ++e) {
                            q[e] = bf2f(rh2[it][0][e]); q[4 + e] = bf2f(rh2[it][1][e]);
                        }
                    } else {
#pragma unroll
                        for (int e = 0; e < 4; ++e) {
                            q[e] = rf2[it][0][e]; q[4 + e] = rf2[it][1][e];
                        }
                    }
#pragma unroll
                    for (int e = 0; e < 8; ++e) v[e] += sc2[k0 + e] * q[e] + sh2[k0 + e];
                } else {
#pragma unroll
                    for (int e = 0; e < 8; ++e) v[e] = v[e] >= 0.f ? v[e] : alpha * v[e];
                }
#pragma unroll
                for (int e = 0; e < 8; ++e) if (ck0[it] + e > 288) v[e] = 0.f;
            } else {
#pragma unroll
                for (int e = 0; e < 8; ++e) v[e] = 0.f;
            }
            u16x4 hi0, hi1, lo0, lo1;
#pragma unroll
            for (int e = 0; e < 4; ++e) {
                unsigned short h = f2bf(v[e]);
                hi0[e] = h; lo0[e] = f2bf_trunc(v[e] - bf2f(h));
                unsigned short h2 = f2bf(v[4 + e]);
                hi1[e] = h2; lo1[e] = f2bf_trunc(v[4 + e] - bf2f(h2));
            }
            int byte = cwb[it];
            *(u16x4*)(As + byte) = hi0;
            *(u16x4*)(As + byte + 8) = hi1;
            *(u16x4*)(As + MROWS * 640 + byte) = lo0;
            *(u16x4*)(As + MROWS * 640 + byte + 8) = lo1;
        }
    };

    LOAD(0);
#pragma unroll 1
    for (int tap = 0; tap < TAPS; ++tap) {
        WRITE();
        if (tap + 1 < TAPS) LOAD(tap + 1);      // in flight across the K-loop
        __syncthreads();
        const bf16* bp = Bs + (size_t)tap * 97280 + (size_t)l * 8;
        int swz = (lane_n & 7) << 4;
        __builtin_amdgcn_s_setprio(1);
#pragma unroll 2
        for (int kt = 0; kt < 10; ++kt) {
            s16x8 ah[MT], al[MT];
#pragma unroll
            for (int m = 0; m < MT; ++m) {
                // XOR after full offset sum: bits 4-6 only, no carry, in-bounds
                int ro = ((m * 16 + lane_n) * 640 + kbyte + kt * 64) ^ swz;
                ah[m] = *(const s16x8*)(As + ro);
                al[m] = *(const s16x8*)(As + MROWS * 640 + ro);
            }
#pragma unroll
            for (int j = 0; j < 5; ++j) {
                if (j < 4 || w < 3) {
                    s16x8 bfr = *(const s16x8*)(bp + (size_t)(kt * 19 + nt0 + j) * 512);
#pragma unroll
                    for (int m = 0; m < MT; ++m) {
                        acc[m][j] = __builtin_amdgcn_mfma_f32_16x16x32_bf16(
                            ah[m], bfr, acc[m][j], 0, 0, 0);
                        acc[m][j] = __builtin_amdgcn_mfma_f32_16x16x32_bf16(
                            al[m], bfr, acc[m][j], 0, 0, 0);
                    }
                }
            }
        }
        __builtin_amdgcn_s_setprio(0);
        __syncthreads();
    }
    // ---- fused BN stats: per-channel sum/sumsq, contiguous per block -------
    {
#pragma unroll
        for (int j = 0; j < 5; ++j) {
            float s = 0.f, ss = 0.f;
            if (j < 4 || w < 3) {
#pragma unroll
                for (int m = 0; m < MT; ++m)
#pragma unroll
                    for (int e = 0; e < 4; ++e) {
                        float v = acc[m][j][e];
                        s += v; ss += v * v;
                    }
            }
            s += __shfl_xor(s, 16); ss += __shfl_xor(ss, 16);
            s += __shfl_xor(s, 32); ss += __shfl_xor(ss, 32);
            int n = (nt0 + j) * 16 + lane_n;
            if (l < 16 && n < 289 && (j < 4 || w < 3)) {
                partial[(long)bid * PST + n] = s;
                partial[(long)bid * PST + 290 + n] = ss;
            }
        }
    }
    // ---- epilogue: acc -> LDS [MROWS][304] -> coalesced row stores ---------
    {
        TO* ep = (TO*)As;
        int re = (l >> 4) << 2;
#pragma unroll
        for (int m = 0; m < MT; ++m) {
#pragma unroll
            for (int j = 0; j < 5; ++j) {
                if (j < 4 || w < 3) {
                    int n = (nt0 + j) * 16 + lane_n;
#pragma unroll
                    for (int e = 0; e < 4; ++e) {
                        if constexpr (sizeof(TO) == 2)
                            ep[(m * 16 + re + e) * 304 + n] = __float2bfloat16(acc[m][j][e]);
                        else
                            ((float*)ep)[(m * 16 + re + e) * 304 + n] = acc[m][j][e];
                    }
                }
            }
        }
        __syncthreads();
        for (int cid = tid; cid < MROWS * 73; cid += 256) {
            int row = cid / 73, j = cid - row * 73;
            long g = (long)(pix0 + row) * CSTR + j * 4;
            if constexpr (sizeof(TO) == 2) {
                u16x4 v = *(const u16x4*)((const bf16*)ep + row * 304 + j * 4);
                *(u16x4*)((bf16*)out + g) = v;
            } else {
                f32x4 v = *(const f32x4*)((const float*)ep + row * 304 + j * 4);
                *(f32x4*)((float*)out + g) = v;
            }
        }
    }
}

// ---- merged idn+y1 kernel: blocks 2..8, 20x20 stride-1, shared staging ------
// One dual-affine staged input feeds TWO B matrices -> two outputs + stats.
__global__ __launch_bounds__(256, 3) void gemm2_k(
    const float* __restrict__ in1, const float* __restrict__ in2,
    float* __restrict__ out1, float* __restrict__ out2,
    const bf16* __restrict__ Bs1, const bf16* __restrict__ Bs2,
    const float* __restrict__ scshAll, int bn1, int bn2,
    float* __restrict__ partial1, float* __restrict__ partial2) {
    constexpr int MROWS = 16;
    __shared__ char As[2 * MROWS * 640];
    __shared__ float sc1[296], sh1[296], sc2[296], sh2[296];
    int tid = threadIdx.x;
    for (int i = tid; i < 296; i += 256) {
        int cc = i < 289 ? i : 0;
        sc1[i] = scshAll[bn1 * 578 + cc]; sh1[i] = scshAll[bn1 * 578 + 289 + cc];
        sc2[i] = scshAll[bn2 * 578 + cc]; sh2[i] = scshAll[bn2 * 578 + 289 + cc];
    }
    if (tid < 128) {
        int half = tid >> 6, r = (tid >> 2) & 15, c = tid & 3;
        int byte = (r * 640 + 576 + c * 16) ^ ((r & 7) << 4);
        *(u16x8*)(As + half * (MROWS * 640) + byte) = (u16x8){0, 0, 0, 0, 0, 0, 0, 0};
    }
    int bid = xcd_swz(blockIdx.x, gridDim.x);
    int pix0 = bid * MROWS;
    int w = tid >> 6, l = tid & 63;
    int nt0 = w * 5, lane_n = l & 15, kbyte = (l >> 4) << 4;
    f32x4 acc1[5], acc2[5];
#pragma unroll
    for (int j = 0; j < 5; ++j) {
        acc1[j] = (f32x4){0.f, 0.f, 0.f, 0.f};
        acc2[j] = (f32x4){0.f, 0.f, 0.f, 0.f};
    }
    __syncthreads();
    // staging: 16 rows x 37 chunks (stride-1 1x1: input pixel == output pixel)
#pragma unroll
    for (int it = 0; it < 3; ++it) {
        int cid = it * 256 + tid;
        if (cid < 592) {
            int row = cid / 37, j = cid - row * 37, k0 = j * 8;
            long gb = (long)(pix0 + row) * CSTR + k0;
            f32x4 a = *(const f32x4*)(in1 + gb), b = *(const f32x4*)(in1 + gb + 4);
            f32x4 c = *(const f32x4*)(in2 + gb), d = *(const f32x4*)(in2 + gb + 4);
            float v[8];
#pragma unroll
            for (int e = 0; e < 4; ++e) {
                v[e] = sc1[k0 + e] * a[e] + sh1[k0 + e] + sc2[k0 + e] * c[e] + sh2[k0 + e];
                v[4 + e] = sc1[k0 + 4 + e] * b[e] + sh1[k0 + 4 + e]
                         + sc2[k0 + 4 + e] * d[e] + sh2[k0 + 4 + e];
            }
#pragma unroll
            for (int e = 0; e < 8; ++e) if (k0 + e > 288) v[e] = 0.f;
            u16x4 hi0, hi1, lo0, lo1;
#pragma unroll
            for (int e = 0; e < 4; ++e) {
                unsigned short h = f2bf(v[e]);
                hi0[e] = h; lo0[e] = f2bf_trunc(v[e] - bf2f(h));
                unsigned short h2 = f2bf(v[4 + e]);
                hi1[e] = h2; lo1[e] = f2bf_trunc(v[4 + e] - bf2f(h2));
            }
            int byte = (row * 640 + j * 16) ^ ((row & 7) << 4);
            *(u16x4*)(As + byte) = hi0;
            *(u16x4*)(As + byte + 8) = hi1;
            *(u16x4*)(As + MROWS * 640 + byte) = lo0;
            *(u16x4*)(As + MROWS * 640 + byte + 8) = lo1;
        }
    }
    __syncthreads();
    const bf16* bp1 = Bs1 + (size_t)l * 8;
    const bf16* bp2 = Bs2 + (size_t)l * 8;
    int swz = (lane_n & 7) << 4;
    __builtin_amdgcn_s_setprio(1);
#pragma unroll 2
    for (int kt = 0; kt < 10; ++kt) {
        int ro = (lane_n * 640 + kbyte + kt * 64) ^ swz;
        s16x8 ah = *(const s16x8*)(As + ro);
        s16x8 al = *(const s16x8*)(As + MROWS * 640 + ro);
#pragma unroll
        for (int j = 0; j < 5; ++j) {
            if (j < 4 || w < 3) {
                size_t fo = (size_t)(kt * 19 + nt0 + j) * 512;
                s16x8 b1 = *(const s16x8*)(bp1 + fo);
                acc1[j] = __builtin_amdgcn_mfma_f32_16x16x32_bf16(ah, b1, acc1[j], 0, 0, 0);
                acc1[j] = __builtin_amdgcn_mfma_f32_16x16x32_bf16(al, b1, acc1[j], 0, 0, 0);
                s16x8 b2 = *(const s16x8*)(bp2 + fo);
                acc2[j] = __builtin_amdgcn_mfma_f32_16x16x32_bf16(ah, b2, acc2[j], 0, 0, 0);
                acc2[j] = __builtin_amdgcn_mfma_f32_16x16x32_bf16(al, b2, acc2[j], 0, 0, 0);
            }
        }
    }
    __builtin_amdgcn_s_setprio(0);
    __syncthreads();
    // ---- stats for both outputs --------------------------------------------
#pragma unroll
    for (int j = 0; j < 5; ++j) {
        float s1 = 0.f, q1 = 0.f, s2 = 0.f, q2 = 0.f;
        if (j < 4 || w < 3) {
#pragma unroll
            for (int e = 0; e < 4; ++e) {
                float v1 = acc1[j][e]; s1 += v1; q1 += v1 * v1;
                float v2 = acc2[j][e]; s2 += v2; q2 += v2 * v2;
            }
        }
        s1 += __shfl_xor(s1, 16); q1 += __shfl_xor(q1, 16);
        s1 += __shfl_xor(s1, 32); q1 += __shfl_xor(q1, 32);
        s2 += __shfl_xor(s2, 16); q2 += __shfl_xor(q2, 16);
        s2 += __shfl_xor(s2, 32); q2 += __shfl_xor(q2, 32);
        int n = (nt0 + j) * 16 + lane_n;
        if (l < 16 && n < 289 && (j < 4 || w < 3)) {
            partial1[(long)bid * PST + n] = s1;
            partial1[(long)bid * PST + 290 + n] = q1;
            partial2[(long)bid * PST + n] = s2;
            partial2[(long)bid * PST + 290 + n] = q2;
        }
    }
    // ---- epilogue x2: acc -> LDS [16][304] -> coalesced row stores ---------
    float* ep = (float*)As;
    int re = (l >> 4) << 2;
#pragma unroll
    for (int pass = 0; pass < 2; ++pass) {
        const f32x4* ac = pass ? acc2 : acc1;
        float* op = pass ? out2 : out1;
#pragma unroll
        for (int j = 0; j < 5; ++j) {
            if (j < 4 || w < 3) {
                int n = (nt0 + j) * 16 + lane_n;
#pragma unroll
                for (int e = 0; e < 4; ++e) ep[(re + e) * 304 + n] = ac[j][e];
            }
        }
        __syncthreads();
        for (int cid = tid; cid < MROWS * 73; cid += 256) {
            int row = cid / 73, j = cid - row * 73;
            long g = (long)(pix0 + row) * CSTR + j * 4;
            f32x4 v = *(const f32x4*)(ep + row * 304 + j * 4);
            *(f32x4*)(op + g) = v;
        }
        __syncthreads();
    }
}

__device__ __forceinline__ void fin_one(const float* partial, const float* g,
                                        const float* bt, float* scshAll,
                                        int bnid, float invN, int GN, int c) {
    float s = 0.f, ss = 0.f;
    for (int k = threadIdx.x; k < GN; k += 256) {
        s += partial[(long)k * PST + c];
        ss += partial[(long)k * PST + 290 + c];
    }
    for (int o = 32; o; o >>= 1) { s += __shfl_down(s, o); ss += __shfl_down(ss, o); }
    __shared__ float ls[4], lss[4];
    int w = threadIdx.x >> 6;
    if ((threadIdx.x & 63) == 0) { ls[w] = s; lss[w] = ss; }
    __syncthreads();
    if (threadIdx.x == 0) {
        s = ls[0] + ls[1] + ls[2] + ls[3];
        ss = lss[0] + lss[1] + lss[2] + lss[3];
        float m = s * invN;
        float v = ss * invN - m * m;
        float sc = g[c] * rsqrtf(v + EPS);
        scshAll[bnid * 578 + c] = sc;
        scshAll[bnid * 578 + 289 + c] = bt[c] - m * sc;
    }
}

__global__ void finalize_k(const float* __restrict__ partial, const float* __restrict__ g,
                           const float* __restrict__ bt, float* __restrict__ scshAll,
                           int bnid, float invN, int GN) {
    fin_one(partial, g, bt, scshAll, bnid, invN, GN, blockIdx.x);
}

// two independent stats sets (possibly different partials / GN / invN)
__global__ void finalize2v_k(const float* __restrict__ pA, const float* __restrict__ pB,
                             const float* __restrict__ gAll, const float* __restrict__ btAll,
                             float* __restrict__ scshAll, int bnA, int bnB,
                             float invA, int GNa, float invB, int GNb) {
    int q = blockIdx.x / 289, c = blockIdx.x - q * 289;
    const float* p = q ? pB : pA;
    int bnid = q ? bnB : bnA;
    fin_one(p, gAll + bnid * 289, btAll + bnid * 289, scshAll, bnid,
            q ? invB : invA, q ? GNb : GNa, c);
}

// ---- final: affine(y3)+affine(idn), NHWC -> NCHW via LDS transpose ----------
__global__ void final_k(const float* __restrict__ y3, const float* __restrict__ idn,
                        float* __restrict__ out, const float* __restrict__ scshAll,
                        int bnY, int bnI) {
    __shared__ float T[32][305];
    int bi = blockIdx.x;          // 32 b x 13 hw-tiles
    int b = bi / 13, t0 = (bi - (bi / 13) * 13) * 32;
    int tid = threadIdx.x;
    int nhw = 400 - t0; if (nhw > 32) nhw = 32;
    for (int idx = tid; idx < 32 * 304; idx += 256) {
        int hwl = idx / 304, c = idx - hwl * 304;
        float v = 0.f;
        if (hwl < nhw && c < 289) {
            long pix = (long)b * 400 + t0 + hwl;
            v = scshAll[bnY * 578 + c] * y3[pix * CSTR + c] + scshAll[bnY * 578 + 289 + c]
              + scshAll[bnI * 578 + c] * idn[pix * CSTR + c] + scshAll[bnI * 578 + 289 + c];
        }
        T[hwl][c] = v;
    }
    __syncthreads();
    for (int idx = tid; idx < 289 * 32; idx += 256) {
        int c = idx >> 5, hwl = idx & 31;
        if (hwl < nhw)
            out[((long)b * 289 + c) * 400 + t0 + hwl] = T[hwl][c];
    }
}

extern "C" void kernel_launch(void* const* d_in, const int* in_sizes, int n_in,
                              void* d_out, int out_size, void* d_ws, size_t ws_size,
                              hipStream_t stream) {
    const float* x     = (const float*)d_in[0];
    const float* fW1   = (const float*)d_in[1];
    const float* fW2   = (const float*)d_in[2];
    const float* c11W1 = (const float*)d_in[4];
    const float* c11W2 = (const float*)d_in[5];
    const float* c33W1 = (const float*)d_in[7];
    const float* c33W2 = (const float*)d_in[8];
    const float* bng   = (const float*)d_in[10];
    const float* bnbt  = (const float*)d_in[11];
    const float* pa    = (const float*)d_in[12];
    float* outp = (float*)d_out;

    char* base = (char*)d_ws;
    bf16*  A    = (bf16*)base;                         // 80x80 bf16: 119,603,200 B
    bf16*  Bb   = (bf16*)(base + 119603200L);          // 40x40 bf16:  29,900,800 B
    bf16*  Cb   = (bf16*)(base + 149504000L);          // 40x40 bf16:  29,900,800 B
    float* scsh = (float*)(base + 179404800L);         // 37*578*4 =       85,544 B
    bf16*  B33s = (bf16*)(base + 179490368L);          // 1710*512*2 =  1,751,040 B
    size_t need = 181241408L;
    if (ws_size < need) return;
    float* D = (float*)base;                           // 20x20 f32 x3 (carved in A)
    float* E = (float*)(base + 14950400L);
    float* F = (float*)(base + 29900800L);
    // dead-A region reuse (A unread after y2_0 finishes):
    float* partialA = (float*)(base + 50000000L);      // 800*PST*4 = 1,856,000 B
    bf16*  B33all   = (bf16*)(base + 100000000L);      // 8*1710*512*2 = 14,008,320 B

    // d_out doubles as scratch until final_k fully overwrites it:
    float* partial = (float*)d_out;                    // <=3200*PST*4 region
    bf16*  B11all  = (bf16*)((char*)d_out + 7424000L); // 27*190*512*2 = 5,253,120 B
    float* partial2 = partial + 800L * PST;            // second stats set (gemm2)
    // big-grid (6400-block) partial for the in-place y1_0 gemm: Cb is dead there
    float* partialBig = (float*)Cb;                    // 6400*PST*4 = 14,848,000 B

    const float inv80 = 1.f / 204800.f, inv40 = 1.f / 51200.f, inv20 = 1.f / 12800.f;

#define B11(cv) (B11all + (size_t)(cv) * 97280)
#define B33A(cv) (B33all + (size_t)((cv) - 1) * 875520)
#define FIN(P, bnid, invN, GN) finalize_k<<<dim3(289), dim3(256), 0, stream>>>( \
        (P), bng + (bnid) * 289, bnbt + (bnid) * 289, scsh, (bnid), (invN), (GN))

    // all 27 1x1 dense-K fragment sets, one launch
    prep11_all_k<<<dim3(27 * 190), dim3(64), 0, stream>>>(c11W1, c11W2, B11all);

    // features -> A (LDS-tiled coalesced stores + fused stats, 2048 partials)
    feat_k<<<dim3(2048), dim3(256), 0, stream>>>(x, A, fW1, fW2, partial);
    FIN(partial, 0, inv80, 2048);

    // block 0 (80 -> 40): input h0 = prelu(aff0(A))
    gemm_k<bf16, bf16, 1, false, 2><<<dim3(1600), dim3(256), 0, stream>>>(
        A, nullptr, Bb, B11(0), scsh, 0, 0, pa + 0, partial, 80, 80, 40, 40, 2);
    gemm_k<bf16, bf16, 1, false, 2><<<dim3(6400), dim3(256), 0, stream>>>(
        A, nullptr, A, B11(9), scsh, 0, 0, pa + 0, partialBig, 80, 80, 80, 80, 1);
    // merged: idn0 stats (bn 1) + y1_0 stats (bn 10)
    finalize2v_k<<<dim3(578), dim3(256), 0, stream>>>(
        partial, partialBig, bng, bnbt, scsh, 1, 10, inv40, 1600, inv80, 6400);
    prep33_k<<<dim3(1710), dim3(64), 0, stream>>>(c33W1, c33W2, B33s);
    gemm_k<bf16, bf16, 9, false, 2><<<dim3(1600), dim3(256), 0, stream>>>(
        A, nullptr, Cb, B33s, scsh, 10, 0, pa + 1, partial, 80, 80, 40, 40, 2);
    // A now dead: build all remaining 3x3 fragment sets (blocks 1..8) at once
    prep33all_k<<<dim3(3420), dim3(256), 0, stream>>>(c33W1, c33W2, B33all);
    FIN(partial, 11, inv40, 1600);                            // y2_0 -> C
    gemm_k<bf16, bf16, 1, false, 2><<<dim3(1600), dim3(256), 0, stream>>>(
        Cb, nullptr, Cb, B11(10), scsh, 11, 0, pa + 2, partial, 40, 40, 40, 40, 1);
    FIN(partial, 12, inv40, 1600);                            // y3_0 -> C (in-place)

    // block 1 (40 -> 20): input h1 = aff12(C) + aff1(B)
    gemm_k<bf16, float, 1, true, 1><<<dim3(800), dim3(256), 0, stream>>>(
        Cb, Bb, D, B11(1), scsh, 12, 1, nullptr, partialA, 40, 40, 20, 20, 2);
    gemm_k<bf16, bf16, 1, true, 2><<<dim3(1600), dim3(256), 0, stream>>>(
        Cb, Bb, Cb, B11(11), scsh, 12, 1, nullptr, partial, 40, 40, 40, 40, 1);
    // merged: idn1 stats (bn 2, partialA) + y1_1 stats (bn 13, partial)
    finalize2v_k<<<dim3(578), dim3(256), 0, stream>>>(
        partialA, partial, bng, bnbt, scsh, 2, 13, inv20, 800, inv40, 1600);
    gemm_k<bf16, float, 9, false, 2><<<dim3(400), dim3(256), 0, stream>>>(
        Cb, nullptr, E, B33A(1), scsh, 13, 0, pa + 3, partial, 40, 40, 20, 20, 2);
    FIN(partial, 14, inv20, 400);                             // y2_1 -> E
    gemm_k<float, float, 1, false, 1><<<dim3(800), dim3(256), 0, stream>>>(
        E, nullptr, E, B11(12), scsh, 14, 0, pa + 4, partial, 20, 20, 20, 20, 1);
    FIN(partial, 15, inv20, 800);                             // y3_1 -> E (in-place)

    // blocks 2..8 (20x20): h_k = aff_{9+3k}(X) + aff_k(Y)
    float *X = E, *Y = D, *Z = F;
    for (int k = 2; k < 9; ++k) {
        // merged idn_k -> Z and y1_k -> X (in-place), shared staging
        gemm2_k<<<dim3(800), dim3(256), 0, stream>>>(
            X, Y, Z, X, B11(k), B11(9 + 2 * k), scsh, 9 + 3 * k, k, partial, partial2);
        finalize2v_k<<<dim3(578), dim3(256), 0, stream>>>(
            partial, partial2, bng, bnbt, scsh, 1 + k, 10 + 3 * k,
            inv20, 800, inv20, 800);
        gemm_k<float, float, 9, false, 2><<<dim3(400), dim3(256), 0, stream>>>(
            X, nullptr, Y, B33A(k), scsh, 10 + 3 * k, 0, pa + 1 + 2 * k, partial,
            20, 20, 20, 20, 1);
        FIN(partial, 11 + 3 * k, inv20, 400);                 // y2_k -> Y
        gemm_k<float, float, 1, false, 1><<<dim3(800), dim3(256), 0, stream>>>(
            Y, nullptr, Y, B11(10 + 2 * k), scsh, 11 + 3 * k, 0, pa + 2 + 2 * k, partial,
            20, 20, 20, 20, 1);
        FIN(partial, 12 + 3 * k, inv20, 800);                 // y3_k -> Y (in-place)
        float* t = X; X = Y; Y = Z; Z = t;                    // exit: X=y3, Y=idn
    }
    final_k<<<dim3(416), dim3(256), 0, stream>>>(X, Y, outp, scsh, 36, 9);
}